// Round 7
// baseline (376.790 us; speedup 1.0000x reference)
//
#include <hip/hip_runtime.h>
#include <math.h>

#define AGENTS 400
#define BATCH  64
#define IDIM   50
#define HDIM   192
#define ODIM   3
#define ADIMM  128
#define NHEADS 8
#define HEADD  16
#define LN_EPS 1e-5f

#define PA   200  // activation LDS pitch in bf16 for out kernel (16B-aligned rows)
#define PAM  192  // mlp activation pitch (384B rows; banking handled by XOR swizzle)
#define POUT 136  // o LDS pitch in bf16 (272 B rows, 16B-aligned)

typedef __bf16 bf16x8 __attribute__((ext_vector_type(8)));
typedef float  f32x4  __attribute__((ext_vector_type(4)));

__device__ __forceinline__ float gelu_exact(float x) {
    return 0.5f * x * (1.0f + erff(x * 0.70710678118654752f));
}

__device__ __forceinline__ unsigned pack_bf16x2(float a, float b) {
    unsigned short ua = __builtin_bit_cast(unsigned short, (__bf16)a);
    unsigned short ub = __builtin_bit_cast(unsigned short, (__bf16)b);
    return (unsigned)ua | ((unsigned)ub << 16);
}

// ---------------------------------------------------------------------------
// Swizzled As accessors (mlp kernel).  8-element bf16 blocks XOR'd with row&7
// so strided fragment reads spread across all 32 banks.
// ---------------------------------------------------------------------------
__device__ __forceinline__ int as_swz(int row, int col) {
    return ((((col >> 3) ^ (row & 7)) << 3) | (col & 7));
}
__device__ __forceinline__ void st_as(__bf16* As_, int row, int col, float v) {
    As_[row * PAM + as_swz(row, col)] = (__bf16)v;
}
__device__ __forceinline__ float ld_as(const __bf16* As_, int row, int col) {
    return (float)As_[row * PAM + as_swz(row, col)];
}
__device__ __forceinline__ bf16x8 ld_afrag(const __bf16* As_, int row, int k0) {
    int blk = (((k0 >> 3) ^ (row & 7)) << 3);
    return *(const bf16x8*)&As_[row * PAM + blk];
}

#define VMWAIT0()   do { asm volatile("s_waitcnt vmcnt(0)" ::: "memory"); \
                         __builtin_amdgcn_sched_barrier(0); } while (0)
#define BARRIER()   do { __builtin_amdgcn_s_barrier(); \
                         __builtin_amdgcn_sched_barrier(0); } while (0)

struct WPtrs { const float *W1, *Ws1, *W2, *Ws2, *W3; };

__device__ __forceinline__ void slot_src(int s, const WPtrs& P,
                                         const float*& M, int& c, int& kdm1)
{
    if (s < 4)       { M = (s & 1) ? P.Ws1 : P.W1; c = s >> 1;      kdm1 = IDIM - 1; }
    else if (s < 16) { int u = s - 4; M = (u & 1) ? P.Ws2 : P.W2; c = u >> 1; kdm1 = HDIM - 1; }
    else             { M = P.W3; c = s - 16; kdm1 = HDIM - 1; }
}

// ---------------------------------------------------------------------------
// Load one K=32 weight chunk (32 x 192 f32) into registers: 6 float4 per
// thread, fully coalesced (linear source).  Latency hides under the current
// slot's compute.
// ---------------------------------------------------------------------------
__device__ __forceinline__ void issue_loads(int s, float4 (&G)[6], const WPtrs& P,
                                            const int* kloc, const int* npl)
{
    const float* M; int c, kdm1;
    slot_src(s, P, M, c, kdm1);
    #pragma unroll
    for (int i = 0; i < 6; i++) {
        int kg = c * 32 + kloc[i];
        kg = (kg <= kdm1) ? kg : kdm1;
        G[i] = *(const float4*)(M + (size_t)kg * HDIM + npl[i]);
    }
}

// ---------------------------------------------------------------------------
// Convert + write one staged chunk to the bf16 LDS ring.  Element (k,n) is
// stored at k*192 + (n ^ ((k>>3)<<3)) so the B-fragment read pattern (8 rows
// of one k-octet at a fixed column) spreads across all 32 banks.
// ---------------------------------------------------------------------------
__device__ __forceinline__ void write_slot(float4 (&G)[6], __bf16* buf,
                                           const int* kloc, const int* npl)
{
    #pragma unroll
    for (int i = 0; i < 6; i++) {
        int k = kloc[i];
        int npe = npl[i] ^ (((k >> 3) & 3) << 3);
        unsigned u0 = pack_bf16x2(G[i].x, G[i].y);
        unsigned u1 = pack_bf16x2(G[i].z, G[i].w);
        *(uint2*)&buf[k * HDIM + npe] = make_uint2(u0, u1);
    }
}

// ---------------------------------------------------------------------------
// One MFMA slot from a bf16 LDS weight chunk: 3 B-frags (24 u16 reads,
// conflict-free via the write swizzle) + 4 A-frags, 12 MFMAs.
// ---------------------------------------------------------------------------
__device__ __forceinline__ void slot_mfma_bf(f32x4 (&acc)[4][3], const __bf16* As_,
                                             const __bf16* Wb, int c, int n0, int lane)
{
    const int r = lane & 15, g = lane >> 4;
    bf16x8 bf[3];
    #pragma unroll
    for (int t = 0; t < 3; t++) {
        int csx = (n0 + 16 * t + r) ^ (g << 3);   // stored column for k-octet g
        #pragma unroll
        for (int j = 0; j < 8; j++)
            bf[t][j] = Wb[(g * 8 + j) * HDIM + csx];
    }
    #pragma unroll
    for (int rg = 0; rg < 4; rg++) {
        bf16x8 af = ld_afrag(As_, 16 * rg + r, c * 32 + g * 8);
        #pragma unroll
        for (int t = 0; t < 3; t++)
            acc[rg][t] = __builtin_amdgcn_mfma_f32_16x16x32_bf16(af, bf[t], acc[rg][t], 0, 0, 0);
    }
}

// ---------------------------------------------------------------------------
// Kernel A: per-agent MLP + fused attention-LN + QKV projection.
// Occupancy round: the weight ring is now bf16 (2 x 12 KB) staged via
// registers (T14: loads issued before compute, LDS write after barrier),
// shrinking LDS to ~49.7 KB -> 3 blocks/CU (was 2).  Per slot:
//   issue_loads(s+1); compute(s); BARRIER; vmcnt(0); write(s+1); syncthreads.
// ---------------------------------------------------------------------------
__global__ __launch_bounds__(256, 2) void mlp_kernel(
    const float* __restrict__ x,
    const float* __restrict__ ln_in_g, const float* __restrict__ ln_in_b,
    const float* __restrict__ W1, const float* __restrict__ b1,
    const float* __restrict__ Ws1, const float* __restrict__ bs1,
    const float* __restrict__ W2, const float* __restrict__ b2,
    const float* __restrict__ Ws2, const float* __restrict__ bs2,
    const float* __restrict__ W3, const float* __restrict__ b3,
    const float* __restrict__ ln_h_g, const float* __restrict__ ln_h_b,
    const float* __restrict__ aln_g, const float* __restrict__ aln_b,
    const float* __restrict__ Wq, const float* __restrict__ bq,
    const float* __restrict__ Wk, const float* __restrict__ bk,
    const float* __restrict__ Wv, const float* __restrict__ bv,
    float* __restrict__ h3out,
    float* __restrict__ qT, float* __restrict__ kT, float* __restrict__ vT)
{
    const int a    = blockIdx.x;
    const int tid  = threadIdx.x;
    const int wave = tid >> 6, lane = tid & 63;
    const int r = lane & 15, g = lane >> 4;
    const int n0 = 48 * wave;

    __shared__ __align__(16) __bf16 As[64 * PAM];        // 24.6 KB
    __shared__ __align__(16) __bf16 Wb[2][32 * HDIM];    // 24.6 KB bf16 ring
    __shared__ float mu_s[64], rs_s[64];

    // per-thread staging geometry: load i covers floats w..w+3,
    // w = i*1024 + tid*4; row k = w/192, col n = w%192 (4-aligned, rows are
    // 192-float so a float4 never crosses a row)
    int kloc[6], npl[6];
    #pragma unroll
    for (int i = 0; i < 6; i++) {
        int w = i * 1024 + tid * 4;
        kloc[i] = w / HDIM;
        npl[i]  = w - kloc[i] * HDIM;
    }

    const WPtrs P = {
        W1  + (size_t)a * IDIM * HDIM,
        Ws1 + (size_t)a * IDIM * HDIM,
        W2  + (size_t)a * HDIM * HDIM,
        Ws2 + (size_t)a * HDIM * HDIM,
        W3  + (size_t)a * HDIM * HDIM };

    float4 G[6];

    // ---- input LN: stats on raw x rows (shared), per-agent affine ----
    {
        int rr = tid >> 2, l = tid & 3;
        float s = 0.f, ss = 0.f;
        for (int k = l; k < IDIM; k += 4) { float v = x[rr * IDIM + k]; s += v; ss += v * v; }
        s  += __shfl_down(s, 2, 4);  s  += __shfl_down(s, 1, 4);
        ss += __shfl_down(ss, 2, 4); ss += __shfl_down(ss, 1, 4);
        if (l == 0) {
            float mu = s * (1.0f / IDIM);
            float var = ss * (1.0f / IDIM) - mu * mu;
            mu_s[rr] = mu;
            rs_s[rr] = rsqrtf(var + LN_EPS);
        }
    }
    __syncthreads();

    issue_loads(0, G, P, kloc, npl);       // slot 0 latency hides under As fill

    for (int sidx = tid; sidx < 64 * 64; sidx += 256) {
        int rr = sidx >> 6, k = sidx & 63;
        float v = 0.f;
        if (k < IDIM)
            v = (x[rr * IDIM + k] - mu_s[rr]) * rs_s[rr] * ln_in_g[a * IDIM + k] + ln_in_b[a * IDIM + k];
        st_as(As, rr, k, v);   // zero-pad k in [IDIM,64)
    }
    VMWAIT0();
    write_slot(G, Wb[0], kloc, npl);
    __syncthreads();           // As + slot 0 visible

    // ======== stage 1: h1 = gelu(xn*W1+b1) + xn*Ws1+bs1  (slots 0-3) ======
    {
        f32x4 acc1[4][3], acc2[4][3];
        #pragma unroll
        for (int i = 0; i < 4; i++)
            #pragma unroll
            for (int t = 0; t < 3; t++) { acc1[i][t] = (f32x4)0.f; acc2[i][t] = (f32x4)0.f; }
        #pragma unroll
        for (int s = 0; s < 4; s++) {
            issue_loads(s + 1, G, P, kloc, npl);
            if ((s & 1) == 0) slot_mfma_bf(acc1, As, Wb[s & 1], s >> 1, n0, lane);
            else              slot_mfma_bf(acc2, As, Wb[s & 1], s >> 1, n0, lane);
            BARRIER();       // all waves done reading Wb[(s+1)&1] (slot s-1)
            VMWAIT0();
            write_slot(G, Wb[(s + 1) & 1], kloc, npl);
            __syncthreads(); // slot s+1 visible
        }
        #pragma unroll
        for (int t = 0; t < 3; t++) {
            int col = n0 + 16 * t + r;
            float bb  = b1[a * HDIM + col];
            float bbs = bs1[a * HDIM + col];
            #pragma unroll
            for (int rg = 0; rg < 4; rg++)
                #pragma unroll
                for (int i = 0; i < 4; i++) {
                    int row = 16 * rg + 4 * g + i;
                    st_as(As, row, col, gelu_exact(acc1[rg][t][i] + bb) + acc2[rg][t][i] + bbs);
                }
        }
        __syncthreads();     // h1 visible; slot 4 already in Wb[0]
    }

    // ======== stage 2: h2 = gelu(h1*W2+b2) + h1*Ws2+bs2  (slots 4-15) =====
    {
        f32x4 acc1[4][3], acc2[4][3];
        #pragma unroll
        for (int i = 0; i < 4; i++)
            #pragma unroll
            for (int t = 0; t < 3; t++) { acc1[i][t] = (f32x4)0.f; acc2[i][t] = (f32x4)0.f; }
        #pragma unroll
        for (int s = 4; s < 16; s++) {
            issue_loads(s + 1, G, P, kloc, npl);
            if ((s & 1) == 0) slot_mfma_bf(acc1, As, Wb[s & 1], (s - 4) >> 1, n0, lane);
            else              slot_mfma_bf(acc2, As, Wb[s & 1], (s - 4) >> 1, n0, lane);
            BARRIER();
            VMWAIT0();
            write_slot(G, Wb[(s + 1) & 1], kloc, npl);
            __syncthreads();
        }
        #pragma unroll
        for (int t = 0; t < 3; t++) {
            int col = n0 + 16 * t + r;
            float bb  = b2[a * HDIM + col];
            float bbs = bs2[a * HDIM + col];
            #pragma unroll
            for (int rg = 0; rg < 4; rg++)
                #pragma unroll
                for (int i = 0; i < 4; i++) {
                    int row = 16 * rg + 4 * g + i;
                    st_as(As, row, col, gelu_exact(acc1[rg][t][i] + bb) + acc2[rg][t][i] + bbs);
                }
        }
        __syncthreads();     // h2 visible; slot 16 already in Wb[0]
    }

    // ======== stage 3: t = h2 + h2*W3 + b3 (slots 16-21), then LN =========
    {
        f32x4 acc[4][3];
        #pragma unroll
        for (int i = 0; i < 4; i++)
            #pragma unroll
            for (int t = 0; t < 3; t++) acc[i][t] = (f32x4)0.f;
        #pragma unroll
        for (int s = 16; s < 22; s++) {
            if (s < 21) issue_loads(s + 1, G, P, kloc, npl);
            slot_mfma_bf(acc, As, Wb[s & 1], s - 16, n0, lane);
            BARRIER();
            if (s < 21) {
                VMWAIT0();
                write_slot(G, Wb[(s + 1) & 1], kloc, npl);
            }
            __syncthreads();
        }
        #pragma unroll
        for (int t = 0; t < 3; t++) {
            int col = n0 + 16 * t + r;
            float bb = b3[a * HDIM + col];
            #pragma unroll
            for (int rg = 0; rg < 4; rg++)
                #pragma unroll
                for (int i = 0; i < 4; i++) {
                    int row = 16 * rg + 4 * g + i;
                    st_as(As, row, col, ld_as(As, row, col) + acc[rg][t][i] + bb);
                }
        }
        __syncthreads();
    }

    // ---- hidden LN -> h3out (f32) AND As (bf16) ----
    {
        int rr = tid >> 2, l = tid & 3;
        float s = 0.f, ss = 0.f;
        for (int k = l; k < HDIM; k += 4) { float v = ld_as(As, rr, k); s += v; ss += v * v; }
        s  += __shfl_down(s, 2, 4);  s  += __shfl_down(s, 1, 4);
        ss += __shfl_down(ss, 2, 4); ss += __shfl_down(ss, 1, 4);
        if (l == 0) {
            float mu = s * (1.0f / HDIM);
            float var = ss * (1.0f / HDIM) - mu * mu;
            mu_s[rr] = mu;
            rs_s[rr] = rsqrtf(var + LN_EPS);
        }
    }
    __syncthreads();
    for (int sidx = tid; sidx < 64 * 48; sidx += 256) {
        int rr = sidx / 48, q = sidx - rr * 48;
        int c = q * 4;
        __bf16* p = &As[rr * PAM + as_swz(rr, c)];
        float4 gv = *(const float4*)&ln_h_g[a * HDIM + c];
        float4 bv = *(const float4*)&ln_h_b[a * HDIM + c];
        float mu = mu_s[rr], rs = rs_s[rr];
        float4 o;
        o.x = ((float)p[0] - mu) * rs * gv.x + bv.x;
        o.y = ((float)p[1] - mu) * rs * gv.y + bv.y;
        o.z = ((float)p[2] - mu) * rs * gv.z + bv.z;
        o.w = ((float)p[3] - mu) * rs * gv.w + bv.w;
        *(float4*)&h3out[((size_t)a * BATCH + rr) * HDIM + c] = o;
        p[0] = (__bf16)o.x; p[1] = (__bf16)o.y; p[2] = (__bf16)o.z; p[3] = (__bf16)o.w;
    }
    __syncthreads();

    // ======== fused attention LN (shared affine) in-place ========
    {
        int rr = tid >> 2, l = tid & 3;
        float s = 0.f, ss = 0.f;
        for (int k = l; k < HDIM; k += 4) { float v = ld_as(As, rr, k); s += v; ss += v * v; }
        s  += __shfl_down(s, 2, 4);  s  += __shfl_down(s, 1, 4);
        ss += __shfl_down(ss, 2, 4); ss += __shfl_down(ss, 1, 4);
        if (l == 0) {
            float mu = s * (1.0f / HDIM);
            float var = ss * (1.0f / HDIM) - mu * mu;
            mu_s[rr] = mu;
            rs_s[rr] = rsqrtf(var + LN_EPS);
        }
    }
    __syncthreads();
    for (int sidx = tid; sidx < 64 * HDIM; sidx += 256) {
        int rr = sidx / HDIM, c = sidx - rr * HDIM;
        float v = (ld_as(As, rr, c) - mu_s[rr]) * rs_s[rr] * aln_g[c] + aln_b[c];
        st_as(As, rr, c, v);
    }
    __syncthreads();

    // ======== fused Q|K|V GEMM (weights L2-resident, reg-streamed) ========
    #pragma unroll
    for (int p = 0; p < 2; p++) {
        const int nb = 192 * p + 48 * wave;
        const float* wA[3];
        #pragma unroll
        for (int t = 0; t < 3; t++) {
            int nt = nb + 16 * t;
            const float* base = (nt < 128) ? Wq : (nt < 256) ? Wk : Wv;
            wA[t] = base + (nt & 127);
        }
        f32x4 acc[4][3];
        #pragma unroll
        for (int i = 0; i < 4; i++)
            #pragma unroll
            for (int t = 0; t < 3; t++) acc[i][t] = (f32x4)0.f;

        float buf[2][24];
        #pragma unroll
        for (int t = 0; t < 3; t++)
            #pragma unroll
            for (int j = 0; j < 8; j++)
                buf[0][t * 8 + j] = wA[t][(g * 8 + j) * ADIMM + r];
        #pragma unroll
        for (int c = 0; c < 6; c++) {
            const int cur = c & 1, nxt = cur ^ 1;
            if (c < 5) {
                #pragma unroll
                for (int t = 0; t < 3; t++)
                    #pragma unroll
                    for (int j = 0; j < 8; j++)
                        buf[nxt][t * 8 + j] = wA[t][((c + 1) * 32 + g * 8 + j) * ADIMM + r];
            }
            bf16x8 bfr[3];
            #pragma unroll
            for (int t = 0; t < 3; t++)
                #pragma unroll
                for (int j = 0; j < 8; j++)
                    bfr[t][j] = (__bf16)buf[cur][t * 8 + j];
            #pragma unroll
            for (int rg = 0; rg < 4; rg++) {
                bf16x8 af = ld_afrag(As, 16 * rg + r, c * 32 + g * 8);
                #pragma unroll
                for (int t = 0; t < 3; t++)
                    acc[rg][t] = __builtin_amdgcn_mfma_f32_16x16x32_bf16(af, bfr[t], acc[rg][t], 0, 0, 0);
            }
        }

        #pragma unroll
        for (int t = 0; t < 3; t++) {
            int n = nb + 16 * t + r;
            int which = n >> 7, cc = n & 127, hh = cc >> 4, dd = cc & 15;
            const float* bp = (which == 0) ? bq : (which == 1) ? bk : bv;
            float* op = (which == 0) ? qT : (which == 1) ? kT : vT;
            float bb = bp[cc];
            #pragma unroll
            for (int rg = 0; rg < 4; rg++)
                #pragma unroll
                for (int i = 0; i < 4; i++) {
                    int brow = 16 * rg + 4 * g + i;
                    op[(((size_t)brow * NHEADS + hh) * AGENTS + a) * HEADD + dd] = acc[rg][t][i] + bb;
                }
        }
    }
}

// ---------------------------------------------------------------------------
// Register-staged GEMM pass (for the small shared-weight GEMM in out).
// ---------------------------------------------------------------------------
template<int NC, int KD, int NT, int NRG, int LDW, int PITCH>
__device__ __forceinline__ void gemm_bpass(f32x4 (&acc)[NRG][NT],
                                           const float* const* wptr,
                                           const __bf16* Asrc, int lane)
{
    const int r = lane & 15, g = lane >> 4;
    float buf[2][NT * 8];

    #pragma unroll
    for (int t = 0; t < NT; t++)
        #pragma unroll
        for (int j = 0; j < 8; j++) {
            int k = g * 8 + j;
            buf[0][t * 8 + j] = (k < KD) ? wptr[t][k * LDW + r] : 0.f;
        }

    #pragma unroll
    for (int c = 0; c < NC; c++) {
        const int cur = c & 1, nxt = cur ^ 1;
        if (c + 1 < NC) {
            #pragma unroll
            for (int t = 0; t < NT; t++)
                #pragma unroll
                for (int j = 0; j < 8; j++) {
                    int k = (c + 1) * 32 + g * 8 + j;
                    buf[nxt][t * 8 + j] = (k < KD) ? wptr[t][k * LDW + r] : 0.f;
                }
        }
        bf16x8 bfr[NT];
        #pragma unroll
        for (int t = 0; t < NT; t++)
            #pragma unroll
            for (int j = 0; j < 8; j++)
                bfr[t][j] = (__bf16)buf[cur][t * 8 + j];
        #pragma unroll
        for (int rg = 0; rg < NRG; rg++) {
            bf16x8 af = *(const bf16x8*)&Asrc[(16 * rg + r) * PITCH + c * 32 + g * 8];
            #pragma unroll
            for (int t = 0; t < NT; t++)
                acc[rg][t] = __builtin_amdgcn_mfma_f32_16x16x32_bf16(af, bfr[t], acc[rg][t], 0, 0, 0);
        }
    }
}

// ---------------------------------------------------------------------------
// Kernel C: cross-agent attention on MFMA.  One block (4 waves) per (b,h).
// This round: Ks pitch 24 -> 44 elements (8-way bank conflict on the hot QK
// b128 reads -> ~2-way).
// ---------------------------------------------------------------------------
#define PKA 44
#define PVA 408
#define PPA 232

__global__ __launch_bounds__(256, 2) void attn_kernel(
    const float* __restrict__ qT, const float* __restrict__ kT,
    const float* __restrict__ vT, float* __restrict__ oT)
{
    const int bh   = blockIdx.x;
    const int b    = bh >> 3, h = bh & 7;
    const int tid  = threadIdx.x;
    const int wave = tid >> 6, lane = tid & 63;
    const int r = lane & 15, g = lane >> 4;

    __shared__ __align__(16) __bf16 Ks[AGENTS * PKA];
    __shared__ __align__(16) __bf16 Vt[16 * PVA];
    __shared__ __align__(16) __bf16 Ps[4][16 * PPA];

    const float* kp = kT + (size_t)bh * AGENTS * HEADD;
    const float* vp = vT + (size_t)bh * AGENTS * HEADD;
    for (int idx4 = tid; idx4 < AGENTS * HEADD / 4; idx4 += 256) {
        int a_ = idx4 >> 2, d0 = (idx4 & 3) << 2;
        float4 kv = *(const float4*)(kp + a_ * HEADD + d0);
        float4 vv = *(const float4*)(vp + a_ * HEADD + d0);
        *(uint2*)&Ks[a_ * PKA + d0] =
            make_uint2(pack_bf16x2(kv.x, kv.y), pack_bf16x2(kv.z, kv.w));
        Vt[(d0 + 0) * PVA + a_] = (__bf16)vv.x;
        Vt[(d0 + 1) * PVA + a_] = (__bf16)vv.y;
        Vt[(d0 + 2) * PVA + a_] = (__bf16)vv.z;
        Vt[(d0 + 3) * PVA + a_] = (__bf16)vv.w;
    }
    __bf16* Pw = Ps[wave];
    for (int z = lane; z < 16 * 16; z += 64)
        Pw[(z >> 4) * PPA + 208 + (z & 15)] = (__bf16)0.f;
    __syncthreads();

    float qf[8];
    auto loadq = [&](int mt_) {
        if (g < 2) {
            const float* qp = qT + ((size_t)bh * AGENTS + mt_ * 16 + r) * HEADD + g * 8;
            float4 v0 = *(const float4*)qp;
            float4 v1 = *(const float4*)(qp + 4);
            qf[0] = v0.x; qf[1] = v0.y; qf[2] = v0.z; qf[3] = v0.w;
            qf[4] = v1.x; qf[5] = v1.y; qf[6] = v1.z; qf[7] = v1.w;
        }
    };
    loadq(wave);

    for (int mt = wave; mt < 25; mt += 4) {
        const int m0 = mt * 16;

        bf16x8 aq;
        #pragma unroll
        for (int j = 0; j < 8; j++)
            aq[j] = (g < 2) ? (__bf16)(qf[j] * 0.25f) : (__bf16)0.f;

        f32x4 sacc[25];
        #pragma unroll
        for (int t = 0; t < 25; t++) {
            bf16x8 bk_ = *(const bf16x8*)&Ks[(t * 16 + r) * PKA + (g & 1) * 8];
            sacc[t] = __builtin_amdgcn_mfma_f32_16x16x32_bf16(aq, bk_, (f32x4)0.f, 0, 0, 0);
        }

        if (mt + 4 < 25) loadq(mt + 4);

        float lv[4];
        #pragma unroll
        for (int i = 0; i < 4; i++) {
            float tm[16];
            #pragma unroll
            for (int t = 0; t < 9; t++) tm[t] = fmaxf(sacc[t][i], sacc[t + 16][i]);
            #pragma unroll
            for (int t = 9; t < 16; t++) tm[t] = sacc[t][i];
            #pragma unroll
            for (int off = 8; off; off >>= 1)
                #pragma unroll
                for (int t = 0; t < off; t++) tm[t] = fmaxf(tm[t], tm[t + off]);
            float m_ = tm[0];
            #pragma unroll
            for (int off = 8; off; off >>= 1) m_ = fmaxf(m_, __shfl_xor(m_, off, 16));

            #pragma unroll
            for (int t = 0; t < 25; t++) sacc[t][i] = __expf(sacc[t][i] - m_);

            float ts[16];
            #pragma unroll
            for (int t = 0; t < 9; t++) ts[t] = sacc[t][i] + sacc[t + 16][i];
            #pragma unroll
            for (int t = 9; t < 16; t++) ts[t] = sacc[t][i];
            #pragma unroll
            for (int off = 8; off; off >>= 1)
                #pragma unroll
                for (int t = 0; t < off; t++) ts[t] += ts[t + off];
            float l_ = ts[0];
            #pragma unroll
            for (int off = 8; off; off >>= 1) l_ += __shfl_xor(l_, off, 16);
            lv[i] = l_;
        }

        f32x4 oacc = (f32x4)0.f;

        #pragma unroll
        for (int t = 0; t < 13; t++)
            #pragma unroll
            for (int i = 0; i < 4; i++)
                Pw[(g * 4 + i) * PPA + t * 16 + r] = (__bf16)sacc[t][i];
        __asm__ volatile("s_waitcnt lgkmcnt(0)" ::: "memory");
        #pragma unroll
        for (int c = 0; c < 7; c++) {
            bf16x8 ap  = *(const bf16x8*)&Pw[r * PPA + c * 32 + g * 8];
            bf16x8 bv_ = *(const bf16x8*)&Vt[r * PVA + c * 32 + g * 8];
            oacc = __builtin_amdgcn_mfma_f32_16x16x32_bf16(ap, bv_, oacc, 0, 0, 0);
        }

        #pragma unroll
        for (int t = 13; t < 25; t++)
            #pragma unroll
            for (int i = 0; i < 4; i++)
                Pw[(g * 4 + i) * PPA + (t - 13) * 16 + r] = (__bf16)sacc[t][i];
        __asm__ volatile("s_waitcnt lgkmcnt(0)" ::: "memory");
        #pragma unroll
        for (int c = 0; c < 6; c++) {
            bf16x8 ap  = *(const bf16x8*)&Pw[r * PPA + c * 32 + g * 8];
            bf16x8 bv_ = *(const bf16x8*)&Vt[r * PVA + 208 + c * 32 + g * 8];
            oacc = __builtin_amdgcn_mfma_f32_16x16x32_bf16(ap, bv_, oacc, 0, 0, 0);
        }

        #pragma unroll
        for (int i = 0; i < 4; i++) {
            float rl = __builtin_amdgcn_rcpf(lv[i]);
            oT[((size_t)(m0 + g * 4 + i) * BATCH + b) * ADIMM + h * HEADD + r] = oacc[i] * rl;
        }
    }
}

// ---------------------------------------------------------------------------
// Kernel D: attended = h3 + o*Wo + bo (MFMA); logits = attended*Wout[a]+bout.
// ---------------------------------------------------------------------------
__global__ __launch_bounds__(256, 2) void out_kernel(
    const float* __restrict__ h3, const float* __restrict__ oT,
    const float* __restrict__ Wo, const float* __restrict__ bo,
    const float* __restrict__ Wout, const float* __restrict__ bout,
    float* __restrict__ out)
{
    const int a    = blockIdx.x;
    const int tid  = threadIdx.x;
    const int wave = tid >> 6, lane = tid & 63;
    const int r = lane & 15, g = lane >> 4;
    const int n0 = 48 * wave;

    __shared__ __align__(16) __bf16 os[64 * POUT];
    __shared__ __align__(16) __bf16 att[64 * PA];
    __shared__ __align__(16) float  wout_s[HDIM * ODIM];

    float h3v[3][4][4];
    #pragma unroll
    for (int t = 0; t < 3; t++) {
        int col = n0 + 16 * t + r;
        #pragma unroll
        for (int rg = 0; rg < 4; rg++)
            #pragma unroll
            for (int i = 0; i < 4; i++)
                h3v[t][rg][i] = h3[((size_t)a * BATCH + 16 * rg + 4 * g + i) * HDIM + col];
    }

    for (int idx = tid; idx < 64 * 32; idx += 256) {
        int bb = idx >> 5, q = idx & 31;
        float4 v = ((const float4*)(oT + ((size_t)a * BATCH + bb) * ADIMM))[q];
        unsigned u0 = pack_bf16x2(v.x, v.y);
        unsigned u1 = pack_bf16x2(v.z, v.w);
        *(uint2*)&os[bb * POUT + q * 4] = make_uint2(u0, u1);
    }
    {
        const float4* src = (const float4*)(Wout + (size_t)a * HDIM * ODIM);
        for (int idx = tid; idx < HDIM * ODIM / 4; idx += 256)
            ((float4*)wout_s)[idx] = src[idx];
    }
    __syncthreads();

    {
        const float* wA[3] = { Wo + n0, Wo + n0 + 16, Wo + n0 + 32 };
        f32x4 acc[4][3];
        #pragma unroll
        for (int i = 0; i < 4; i++)
            #pragma unroll
            for (int t = 0; t < 3; t++) acc[i][t] = (f32x4)0.f;
        gemm_bpass<4, ADIMM, 3, 4, HDIM, POUT>(acc, wA, os, lane);
        #pragma unroll
        for (int t = 0; t < 3; t++) {
            int col = n0 + 16 * t + r;
            float bb = bo[col];
            #pragma unroll
            for (int rg = 0; rg < 4; rg++)
                #pragma unroll
                for (int i = 0; i < 4; i++) {
                    int row = 16 * rg + 4 * g + i;
                    float v = h3v[t][rg][i] + acc[rg][t][i] + bb;
                    att[row * PA + col] = (__bf16)v;
                }
        }
    }
    __syncthreads();

    {
        float wb[48];
        #pragma unroll
        for (int c = 0; c < 6; c++)
            #pragma unroll
            for (int j = 0; j < 8; j++) {
                int k = c * 32 + g * 8 + j;
                wb[c * 8 + j] = (r < ODIM) ? wout_s[k * ODIM + r] : 0.f;
            }
        f32x4 oacc = (f32x4)0.f;
        #pragma unroll
        for (int c = 0; c < 6; c++) {
            bf16x8 bf;
            #pragma unroll
            for (int j = 0; j < 8; j++) bf[j] = (__bf16)wb[c * 8 + j];
            bf16x8 af = *(const bf16x8*)&att[(16 * wave + r) * PA + c * 32 + g * 8];
            oacc = __builtin_amdgcn_mfma_f32_16x16x32_bf16(af, bf, oacc, 0, 0, 0);
        }
        if (r < ODIM) {
            float bb = bout[a * ODIM + r];
            #pragma unroll
            for (int i = 0; i < 4; i++) {
                int row = 16 * wave + 4 * g + i;
                out[((size_t)a * BATCH + row) * ODIM + r] = oacc[i] + bb;
            }
        }
    }
}

// ---------------------------------------------------------------------------
extern "C" void kernel_launch(void* const* d_in, const int* in_sizes, int n_in,
                              void* d_out, int out_size, void* d_ws, size_t ws_size,
                              hipStream_t stream)
{
    const float* x       = (const float*)d_in[0];
    const float* ln_in_g = (const float*)d_in[1];
    const float* ln_in_b = (const float*)d_in[2];
    const float* W1      = (const float*)d_in[3];
    const float* b1      = (const float*)d_in[4];
    const float* Ws1     = (const float*)d_in[5];
    const float* bs1     = (const float*)d_in[6];
    const float* W2      = (const float*)d_in[7];
    const float* b2      = (const float*)d_in[8];
    const float* Ws2     = (const float*)d_in[9];
    const float* bs2     = (const float*)d_in[10];
    const float* W3      = (const float*)d_in[11];
    const float* b3      = (const float*)d_in[12];
    const float* ln_h_g  = (const float*)d_in[13];
    const float* ln_h_b  = (const float*)d_in[14];
    const float* Wout    = (const float*)d_in[15];
    const float* bout    = (const float*)d_in[16];
    const float* aln_g   = (const float*)d_in[17];
    const float* aln_b   = (const float*)d_in[18];
    const float* Wq      = (const float*)d_in[19];
    const float* bq      = (const float*)d_in[20];
    const float* Wk      = (const float*)d_in[21];
    const float* bk      = (const float*)d_in[22];
    const float* Wv      = (const float*)d_in[23];
    const float* bv      = (const float*)d_in[24];
    const float* Wo      = (const float*)d_in[25];
    const float* bo      = (const float*)d_in[26];
    float* out = (float*)d_out;

    float* ws = (float*)d_ws;
    const size_t H3_SZ = (size_t)AGENTS * BATCH * HDIM;
    const size_t QT_SZ = (size_t)BATCH * NHEADS * AGENTS * HEADD;
    float* h3 = ws;
    float* qT = h3 + H3_SZ;
    float* kT = qT + QT_SZ;
    float* vT = kT + QT_SZ;
    float* oT = vT + QT_SZ;

    mlp_kernel<<<AGENTS, 256, 0, stream>>>(x, ln_in_g, ln_in_b,
                                           W1, b1, Ws1, bs1, W2, b2, Ws2, bs2,
                                           W3, b3, ln_h_g, ln_h_b,
                                           aln_g, aln_b, Wq, bq, Wk, bk, Wv, bv,
                                           h3, qT, kT, vT);
    attn_kernel<<<BATCH * NHEADS, 256, 0, stream>>>(qT, kT, vT, oT);
    out_kernel<<<AGENTS, 256, 0, stream>>>(h3, oT, Wo, bo, Wout, bout, out);
}

// Round 8
// 364.260 us; speedup vs baseline: 1.0344x; 1.0344x over previous
//
#include <hip/hip_runtime.h>
#include <math.h>

#define AGENTS 400
#define BATCH  64
#define IDIM   50
#define HDIM   192
#define ODIM   3
#define ADIMM  128
#define NHEADS 8
#define HEADD  16
#define LN_EPS 1e-5f

#define PA   200  // activation LDS pitch in bf16 for out kernel (16B-aligned rows)
#define PAM  192  // mlp activation pitch (384B rows; banking handled by XOR swizzle)
#define POUT 136  // o LDS pitch in bf16 (272 B rows, 16B-aligned)
#define MROWS 32  // batch rows per mlp block (2 blocks per agent)

typedef __bf16 bf16x8 __attribute__((ext_vector_type(8)));
typedef float  f32x4  __attribute__((ext_vector_type(4)));

__device__ __forceinline__ float gelu_exact(float x) {
    return 0.5f * x * (1.0f + erff(x * 0.70710678118654752f));
}

__device__ __forceinline__ unsigned pack_bf16x2(float a, float b) {
    unsigned short ua = __builtin_bit_cast(unsigned short, (__bf16)a);
    unsigned short ub = __builtin_bit_cast(unsigned short, (__bf16)b);
    return (unsigned)ua | ((unsigned)ub << 16);
}

// ---------------------------------------------------------------------------
// Swizzled As accessors (mlp kernel).  8-element bf16 blocks XOR'd with row&7
// so strided fragment reads spread across all 32 banks.
// ---------------------------------------------------------------------------
__device__ __forceinline__ int as_swz(int row, int col) {
    return ((((col >> 3) ^ (row & 7)) << 3) | (col & 7));
}
__device__ __forceinline__ void st_as(__bf16* As_, int row, int col, float v) {
    As_[row * PAM + as_swz(row, col)] = (__bf16)v;
}
__device__ __forceinline__ float ld_as(const __bf16* As_, int row, int col) {
    return (float)As_[row * PAM + as_swz(row, col)];
}
__device__ __forceinline__ bf16x8 ld_afrag(const __bf16* As_, int row, int k0) {
    int blk = (((k0 >> 3) ^ (row & 7)) << 3);
    return *(const bf16x8*)&As_[row * PAM + blk];
}

// ---------------------------------------------------------------------------
// Pipeline sync primitives (round-3 verified schedule: issue(next);
// compute(cur); vmcnt(0); s_barrier).
// ---------------------------------------------------------------------------
#define VMWAIT0()   do { asm volatile("s_waitcnt vmcnt(0)" ::: "memory"); \
                         __builtin_amdgcn_sched_barrier(0); } while (0)
#define BARRIER()   do { __builtin_amdgcn_s_barrier(); \
                         __builtin_amdgcn_sched_barrier(0); } while (0)

struct WPtrs { const float *W1, *Ws1, *W2, *Ws2, *W3; };

// ---------------------------------------------------------------------------
// Issue one K=32 weight chunk (32 x 192 f32 = 24 KB) as 6 async
// global_load_lds dwordx4 per thread.  LDS dest is linear; the global SOURCE
// column is pre-swizzled (n' = n ^ (k_octet<<3)) so the B-fragment
// ds_read_b32 pattern is 2-way banked.  Slot order:
// [W1c0 Ws1c0 W1c1 Ws1c1 | W2c0 Ws2c0 .. Ws2c5 | W3c0..W3c5].
// ---------------------------------------------------------------------------
__device__ __forceinline__ void issue_slot(int s, float* buf0, float* buf1,
                                           const WPtrs& P, const int* kloc,
                                           const int* nsw, int tid)
{
    const float* M; int c, kdm1;
    if (s < 4)       { M = (s & 1) ? P.Ws1 : P.W1; c = s >> 1;      kdm1 = IDIM - 1; }
    else if (s < 16) { int u = s - 4; M = (u & 1) ? P.Ws2 : P.W2; c = u >> 1; kdm1 = HDIM - 1; }
    else             { M = P.W3; c = s - 16; kdm1 = HDIM - 1; }
    float* dst = (s & 1) ? buf1 : buf0;
    #pragma unroll
    for (int i = 0; i < 6; i++) {
        int kg = c * 32 + kloc[i];
        kg = (kg <= kdm1) ? kg : kdm1;
        const float* src = M + (size_t)kg * HDIM + nsw[i];
        __builtin_amdgcn_global_load_lds(
            (const __attribute__((address_space(1))) void*)src,
            (__attribute__((address_space(3))) void*)(dst + (i * 256 + tid) * 4),
            16, 0, 0);
    }
    __builtin_amdgcn_sched_barrier(0);
}

// ---------------------------------------------------------------------------
// One MFMA slot from an f32 LDS weight chunk: build 3 B-frags (24 ds_read_b32,
// swizzled columns, 2-way banked) + 2 A-frags (32 rows), 6 MFMAs.
// ---------------------------------------------------------------------------
__device__ __forceinline__ void slot_mfma_f32(f32x4 (&acc)[2][3], const __bf16* As_,
                                              const float* Wbuf, int c, int n0, int lane)
{
    const int r = lane & 15, g = lane >> 4;
    bf16x8 bf[3];
    #pragma unroll
    for (int t = 0; t < 3; t++) {
        int cs = (n0 + 16 * t + r) ^ (g << 3);   // undo source pre-swizzle
        #pragma unroll
        for (int j = 0; j < 8; j++)
            bf[t][j] = (__bf16)Wbuf[(g * 8 + j) * HDIM + cs];
    }
    #pragma unroll
    for (int rg = 0; rg < 2; rg++) {
        bf16x8 af = ld_afrag(As_, 16 * rg + r, c * 32 + g * 8);
        #pragma unroll
        for (int t = 0; t < 3; t++)
            acc[rg][t] = __builtin_amdgcn_mfma_f32_16x16x32_bf16(af, bf[t], acc[rg][t], 0, 0, 0);
    }
}

// ---------------------------------------------------------------------------
// Kernel A: per-agent MLP + fused attention-LN + QKV projection.
// Grid split round: TWO blocks per agent (32 batch rows each), grid = 800.
// Blocks bid and bid+400 share an agent; 400 % 8 == 0 so twins land on the
// SAME XCD and their duplicate weight stream is served by L2/L3 (whole
// weight set = 207 MB < 256 MB L3).  More resident blocks/CU (1.56 -> 2.0
// packed) + halved per-block compute attack the latency-TLP limit that
// pinned every schedule at ~1.3 TB/s.
// ---------------------------------------------------------------------------
__global__ __launch_bounds__(256, 2) void mlp_kernel(
    const float* __restrict__ x,
    const float* __restrict__ ln_in_g, const float* __restrict__ ln_in_b,
    const float* __restrict__ W1, const float* __restrict__ b1,
    const float* __restrict__ Ws1, const float* __restrict__ bs1,
    const float* __restrict__ W2, const float* __restrict__ b2,
    const float* __restrict__ Ws2, const float* __restrict__ bs2,
    const float* __restrict__ W3, const float* __restrict__ b3,
    const float* __restrict__ ln_h_g, const float* __restrict__ ln_h_b,
    const float* __restrict__ aln_g, const float* __restrict__ aln_b,
    const float* __restrict__ Wq, const float* __restrict__ bq,
    const float* __restrict__ Wk, const float* __restrict__ bk,
    const float* __restrict__ Wv, const float* __restrict__ bv,
    float* __restrict__ h3out,
    float* __restrict__ qT, float* __restrict__ kT, float* __restrict__ vT)
{
    const int bid  = blockIdx.x;
    const int a    = bid % AGENTS;            // twins (bid, bid+400): same XCD
    const int rb   = (bid / AGENTS) * MROWS;  // batch-row base (0 or 32)
    const int tid  = threadIdx.x;
    const int wave = tid >> 6, lane = tid & 63;
    const int r = lane & 15, g = lane >> 4;
    const int n0 = 48 * wave;

    __shared__ __align__(16) __bf16 As[MROWS * PAM];     // 12.3 KB
    __shared__ __align__(16) float  Wbuf[2][32 * HDIM];  // 48 KB ring
    __shared__ float mu_s[MROWS], rs_s[MROWS];

    // per-thread staging geometry: load i covers LDS words w..w+3,
    // w = i*1024 + tid*4; row k = w/192, col n' = w%192 (4-aligned);
    // global col n = n' ^ ((k>>3)<<3).
    int kloc[6], nsw[6];
    #pragma unroll
    for (int i = 0; i < 6; i++) {
        int w = i * 1024 + tid * 4;
        kloc[i] = w / HDIM;
        int np = w - kloc[i] * HDIM;
        nsw[i] = np ^ (((kloc[i] >> 3) & 3) << 3);
    }

    const WPtrs P = {
        W1  + (size_t)a * IDIM * HDIM,
        Ws1 + (size_t)a * IDIM * HDIM,
        W2  + (size_t)a * HDIM * HDIM,
        Ws2 + (size_t)a * HDIM * HDIM,
        W3  + (size_t)a * HDIM * HDIM };

    // ---- input LN: stats on raw x rows (8 threads/row over 32 rows) ----
    {
        int rr = tid >> 3, l = tid & 7;
        const float* xp = x + (size_t)(rb + rr) * IDIM;
        float s = 0.f, ss = 0.f;
        for (int k = l; k < IDIM; k += 8) { float v = xp[k]; s += v; ss += v * v; }
        s  += __shfl_down(s, 4, 8); s  += __shfl_down(s, 2, 8); s  += __shfl_down(s, 1, 8);
        ss += __shfl_down(ss, 4, 8); ss += __shfl_down(ss, 2, 8); ss += __shfl_down(ss, 1, 8);
        if (l == 0) {
            float mu = s * (1.0f / IDIM);
            float var = ss * (1.0f / IDIM) - mu * mu;
            mu_s[rr] = mu;
            rs_s[rr] = rsqrtf(var + LN_EPS);
        }
    }
    __syncthreads();

    issue_slot(0, Wbuf[0], Wbuf[1], P, kloc, nsw, tid);  // hides under As fill

    for (int sidx = tid; sidx < MROWS * 64; sidx += 256) {
        int rr = sidx >> 6, k = sidx & 63;
        float v = 0.f;
        if (k < IDIM)
            v = (x[(size_t)(rb + rr) * IDIM + k] - mu_s[rr]) * rs_s[rr]
                * ln_in_g[a * IDIM + k] + ln_in_b[a * IDIM + k];
        st_as(As, rr, k, v);   // zero-pad k in [IDIM,64)
    }
    __syncthreads();           // drains vmcnt: slot 0 resident for all waves

    // ======== stage 1: h1 = gelu(xn*W1+b1) + xn*Ws1+bs1  (slots 0-3) ======
    {
        f32x4 acc1[2][3], acc2[2][3];
        #pragma unroll
        for (int i = 0; i < 2; i++)
            #pragma unroll
            for (int t = 0; t < 3; t++) { acc1[i][t] = (f32x4)0.f; acc2[i][t] = (f32x4)0.f; }
        #pragma unroll
        for (int s = 0; s < 4; s++) {
            if (s < 3) issue_slot(s + 1, Wbuf[0], Wbuf[1], P, kloc, nsw, tid);
            if ((s & 1) == 0) slot_mfma_f32(acc1, As, Wbuf[s & 1], s >> 1, n0, lane);
            else              slot_mfma_f32(acc2, As, Wbuf[s & 1], s >> 1, n0, lane);
            VMWAIT0();
            BARRIER();
        }
        issue_slot(4, Wbuf[0], Wbuf[1], P, kloc, nsw, tid);   // lands under epilogue
        #pragma unroll
        for (int t = 0; t < 3; t++) {
            int col = n0 + 16 * t + r;
            float bb  = b1[a * HDIM + col];
            float bbs = bs1[a * HDIM + col];
            #pragma unroll
            for (int rg = 0; rg < 2; rg++)
                #pragma unroll
                for (int i = 0; i < 4; i++) {
                    int row = 16 * rg + 4 * g + i;
                    st_as(As, row, col, gelu_exact(acc1[rg][t][i] + bb) + acc2[rg][t][i] + bbs);
                }
        }
        __syncthreads();     // h1 visible; slot 4 resident
    }

    // ======== stage 2: h2 = gelu(h1*W2+b2) + h1*Ws2+bs2  (slots 4-15) =====
    {
        f32x4 acc1[2][3], acc2[2][3];
        #pragma unroll
        for (int i = 0; i < 2; i++)
            #pragma unroll
            for (int t = 0; t < 3; t++) { acc1[i][t] = (f32x4)0.f; acc2[i][t] = (f32x4)0.f; }
        #pragma unroll
        for (int s = 4; s < 16; s++) {
            if (s < 15) issue_slot(s + 1, Wbuf[0], Wbuf[1], P, kloc, nsw, tid);
            if ((s & 1) == 0) slot_mfma_f32(acc1, As, Wbuf[s & 1], (s - 4) >> 1, n0, lane);
            else              slot_mfma_f32(acc2, As, Wbuf[s & 1], (s - 4) >> 1, n0, lane);
            VMWAIT0();
            BARRIER();
        }
        issue_slot(16, Wbuf[0], Wbuf[1], P, kloc, nsw, tid);  // lands under epilogue
        #pragma unroll
        for (int t = 0; t < 3; t++) {
            int col = n0 + 16 * t + r;
            float bb  = b2[a * HDIM + col];
            float bbs = bs2[a * HDIM + col];
            #pragma unroll
            for (int rg = 0; rg < 2; rg++)
                #pragma unroll
                for (int i = 0; i < 4; i++) {
                    int row = 16 * rg + 4 * g + i;
                    st_as(As, row, col, gelu_exact(acc1[rg][t][i] + bb) + acc2[rg][t][i] + bbs);
                }
        }
        __syncthreads();     // h2 visible; slot 16 resident
    }

    // ======== stage 3: t = h2 + h2*W3 + b3 (slots 16-21), then LN =========
    {
        f32x4 acc[2][3];
        #pragma unroll
        for (int i = 0; i < 2; i++)
            #pragma unroll
            for (int t = 0; t < 3; t++) acc[i][t] = (f32x4)0.f;
        #pragma unroll
        for (int s = 16; s < 22; s++) {
            if (s < 21) issue_slot(s + 1, Wbuf[0], Wbuf[1], P, kloc, nsw, tid);
            slot_mfma_f32(acc, As, Wbuf[s & 1], s - 16, n0, lane);
            VMWAIT0();
            BARRIER();
        }
        #pragma unroll
        for (int t = 0; t < 3; t++) {
            int col = n0 + 16 * t + r;
            float bb = b3[a * HDIM + col];
            #pragma unroll
            for (int rg = 0; rg < 2; rg++)
                #pragma unroll
                for (int i = 0; i < 4; i++) {
                    int row = 16 * rg + 4 * g + i;
                    st_as(As, row, col, ld_as(As, row, col) + acc[rg][t][i] + bb);
                }
        }
        __syncthreads();
    }

    // ---- hidden LN -> h3out (f32) AND As (bf16) ----
    {
        int rr = tid >> 3, l = tid & 7;
        float s = 0.f, ss = 0.f;
        for (int k = l; k < HDIM; k += 8) { float v = ld_as(As, rr, k); s += v; ss += v * v; }
        s  += __shfl_down(s, 4, 8); s  += __shfl_down(s, 2, 8); s  += __shfl_down(s, 1, 8);
        ss += __shfl_down(ss, 4, 8); ss += __shfl_down(ss, 2, 8); ss += __shfl_down(ss, 1, 8);
        if (l == 0) {
            float mu = s * (1.0f / HDIM);
            float var = ss * (1.0f / HDIM) - mu * mu;
            mu_s[rr] = mu;
            rs_s[rr] = rsqrtf(var + LN_EPS);
        }
    }
    __syncthreads();
    for (int sidx = tid; sidx < MROWS * 48; sidx += 256) {
        int rr = sidx / 48, q = sidx - rr * 48;
        int c = q * 4;                                     // c%8 in {0,4}: one swizzle block
        __bf16* p = &As[rr * PAM + as_swz(rr, c)];
        float4 gv = *(const float4*)&ln_h_g[a * HDIM + c];
        float4 bv = *(const float4*)&ln_h_b[a * HDIM + c];
        float mu = mu_s[rr], rs = rs_s[rr];
        float4 o;
        o.x = ((float)p[0] - mu) * rs * gv.x + bv.x;
        o.y = ((float)p[1] - mu) * rs * gv.y + bv.y;
        o.z = ((float)p[2] - mu) * rs * gv.z + bv.z;
        o.w = ((float)p[3] - mu) * rs * gv.w + bv.w;
        *(float4*)&h3out[((size_t)a * BATCH + rb + rr) * HDIM + c] = o;
        p[0] = (__bf16)o.x; p[1] = (__bf16)o.y; p[2] = (__bf16)o.z; p[3] = (__bf16)o.w;
    }
    __syncthreads();

    // ======== fused attention LN (shared affine) in-place ========
    {
        int rr = tid >> 3, l = tid & 7;
        float s = 0.f, ss = 0.f;
        for (int k = l; k < HDIM; k += 8) { float v = ld_as(As, rr, k); s += v; ss += v * v; }
        s  += __shfl_down(s, 4, 8); s  += __shfl_down(s, 2, 8); s  += __shfl_down(s, 1, 8);
        ss += __shfl_down(ss, 4, 8); ss += __shfl_down(ss, 2, 8); ss += __shfl_down(ss, 1, 8);
        if (l == 0) {
            float mu = s * (1.0f / HDIM);
            float var = ss * (1.0f / HDIM) - mu * mu;
            mu_s[rr] = mu;
            rs_s[rr] = rsqrtf(var + LN_EPS);
        }
    }
    __syncthreads();
    for (int sidx = tid; sidx < MROWS * HDIM; sidx += 256) {
        int rr = sidx / HDIM, c = sidx - rr * HDIM;
        float v = (ld_as(As, rr, c) - mu_s[rr]) * rs_s[rr] * aln_g[c] + aln_b[c];
        st_as(As, rr, c, v);   // each cell touched by exactly one thread
    }
    __syncthreads();

    // ======== fused Q|K|V GEMM (weights L2-resident, reg-streamed) ========
    #pragma unroll
    for (int p = 0; p < 2; p++) {
        const int nb = 192 * p + 48 * wave;
        const float* wA[3];
        #pragma unroll
        for (int t = 0; t < 3; t++) {
            int nt = nb + 16 * t;
            const float* base = (nt < 128) ? Wq : (nt < 256) ? Wk : Wv;
            wA[t] = base + (nt & 127);
        }
        f32x4 acc[2][3];
        #pragma unroll
        for (int i = 0; i < 2; i++)
            #pragma unroll
            for (int t = 0; t < 3; t++) acc[i][t] = (f32x4)0.f;

        float buf[2][24];
        #pragma unroll
        for (int t = 0; t < 3; t++)
            #pragma unroll
            for (int j = 0; j < 8; j++)
                buf[0][t * 8 + j] = wA[t][(g * 8 + j) * ADIMM + r];
        #pragma unroll
        for (int c = 0; c < 6; c++) {
            const int cur = c & 1, nxt = cur ^ 1;
            if (c < 5) {
                #pragma unroll
                for (int t = 0; t < 3; t++)
                    #pragma unroll
                    for (int j = 0; j < 8; j++)
                        buf[nxt][t * 8 + j] = wA[t][((c + 1) * 32 + g * 8 + j) * ADIMM + r];
            }
            bf16x8 bfr[3];
            #pragma unroll
            for (int t = 0; t < 3; t++)
                #pragma unroll
                for (int j = 0; j < 8; j++)
                    bfr[t][j] = (__bf16)buf[cur][t * 8 + j];
            #pragma unroll
            for (int rg = 0; rg < 2; rg++) {
                bf16x8 af = ld_afrag(As, 16 * rg + r, c * 32 + g * 8);
                #pragma unroll
                for (int t = 0; t < 3; t++)
                    acc[rg][t] = __builtin_amdgcn_mfma_f32_16x16x32_bf16(af, bfr[t], acc[rg][t], 0, 0, 0);
            }
        }

        #pragma unroll
        for (int t = 0; t < 3; t++) {
            int n = nb + 16 * t + r;
            int which = n >> 7, cc = n & 127, hh = cc >> 4, dd = cc & 15;
            const float* bp = (which == 0) ? bq : (which == 1) ? bk : bv;
            float* op = (which == 0) ? qT : (which == 1) ? kT : vT;
            float bb = bp[cc];
            #pragma unroll
            for (int rg = 0; rg < 2; rg++)
                #pragma unroll
                for (int i = 0; i < 4; i++) {
                    int brow = rb + 16 * rg + 4 * g + i;
                    op[(((size_t)brow * NHEADS + hh) * AGENTS + a) * HEADD + dd] = acc[rg][t][i] + bb;
                }
        }
    }
}

// ---------------------------------------------------------------------------
// Register-staged GEMM pass (for the small shared-weight GEMM in out).
// ---------------------------------------------------------------------------
template<int NC, int KD, int NT, int NRG, int LDW, int PITCH>
__device__ __forceinline__ void gemm_bpass(f32x4 (&acc)[NRG][NT],
                                           const float* const* wptr,
                                           const __bf16* Asrc, int lane)
{
    const int r = lane & 15, g = lane >> 4;
    float buf[2][NT * 8];

    #pragma unroll
    for (int t = 0; t < NT; t++)
        #pragma unroll
        for (int j = 0; j < 8; j++) {
            int k = g * 8 + j;
            buf[0][t * 8 + j] = (k < KD) ? wptr[t][k * LDW + r] : 0.f;
        }

    #pragma unroll
    for (int c = 0; c < NC; c++) {
        const int cur = c & 1, nxt = cur ^ 1;
        if (c + 1 < NC) {
            #pragma unroll
            for (int t = 0; t < NT; t++)
                #pragma unroll
                for (int j = 0; j < 8; j++) {
                    int k = (c + 1) * 32 + g * 8 + j;
                    buf[nxt][t * 8 + j] = (k < KD) ? wptr[t][k * LDW + r] : 0.f;
                }
        }
        bf16x8 bfr[NT];
        #pragma unroll
        for (int t = 0; t < NT; t++)
            #pragma unroll
            for (int j = 0; j < 8; j++)
                bfr[t][j] = (__bf16)buf[cur][t * 8 + j];
        #pragma unroll
        for (int rg = 0; rg < NRG; rg++) {
            bf16x8 af = *(const bf16x8*)&Asrc[(16 * rg + r) * PITCH + c * 32 + g * 8];
            #pragma unroll
            for (int t = 0; t < NT; t++)
                acc[rg][t] = __builtin_amdgcn_mfma_f32_16x16x32_bf16(af, bfr[t], acc[rg][t], 0, 0, 0);
        }
    }
}

// ---------------------------------------------------------------------------
// Kernel C: cross-agent attention on MFMA.  One block (4 waves) per (b,h).
// (exact 356.8-us build: float4 K/V staging, Q double-buffer, tree
// reductions, rcp epilogue)
// ---------------------------------------------------------------------------
#define PKA 24
#define PVA 408
#define PPA 232

__global__ __launch_bounds__(256, 2) void attn_kernel(
    const float* __restrict__ qT, const float* __restrict__ kT,
    const float* __restrict__ vT, float* __restrict__ oT)
{
    const int bh   = blockIdx.x;
    const int b    = bh >> 3, h = bh & 7;
    const int tid  = threadIdx.x;
    const int wave = tid >> 6, lane = tid & 63;
    const int r = lane & 15, g = lane >> 4;

    __shared__ __align__(16) __bf16 Ks[AGENTS * PKA];
    __shared__ __align__(16) __bf16 Vt[16 * PVA];
    __shared__ __align__(16) __bf16 Ps[4][16 * PPA];

    const float* kp = kT + (size_t)bh * AGENTS * HEADD;
    const float* vp = vT + (size_t)bh * AGENTS * HEADD;
    for (int idx4 = tid; idx4 < AGENTS * HEADD / 4; idx4 += 256) {
        int a_ = idx4 >> 2, d0 = (idx4 & 3) << 2;
        float4 kv = *(const float4*)(kp + a_ * HEADD + d0);
        float4 vv = *(const float4*)(vp + a_ * HEADD + d0);
        *(uint2*)&Ks[a_ * PKA + d0] =
            make_uint2(pack_bf16x2(kv.x, kv.y), pack_bf16x2(kv.z, kv.w));
        Vt[(d0 + 0) * PVA + a_] = (__bf16)vv.x;
        Vt[(d0 + 1) * PVA + a_] = (__bf16)vv.y;
        Vt[(d0 + 2) * PVA + a_] = (__bf16)vv.z;
        Vt[(d0 + 3) * PVA + a_] = (__bf16)vv.w;
    }
    __bf16* Pw = Ps[wave];
    for (int z = lane; z < 16 * 16; z += 64)
        Pw[(z >> 4) * PPA + 208 + (z & 15)] = (__bf16)0.f;
    __syncthreads();

    float qf[8];
    auto loadq = [&](int mt_) {
        if (g < 2) {
            const float* qp = qT + ((size_t)bh * AGENTS + mt_ * 16 + r) * HEADD + g * 8;
            float4 v0 = *(const float4*)qp;
            float4 v1 = *(const float4*)(qp + 4);
            qf[0] = v0.x; qf[1] = v0.y; qf[2] = v0.z; qf[3] = v0.w;
            qf[4] = v1.x; qf[5] = v1.y; qf[6] = v1.z; qf[7] = v1.w;
        }
    };
    loadq(wave);

    for (int mt = wave; mt < 25; mt += 4) {
        const int m0 = mt * 16;

        bf16x8 aq;
        #pragma unroll
        for (int j = 0; j < 8; j++)
            aq[j] = (g < 2) ? (__bf16)(qf[j] * 0.25f) : (__bf16)0.f;

        f32x4 sacc[25];
        #pragma unroll
        for (int t = 0; t < 25; t++) {
            bf16x8 bk_ = *(const bf16x8*)&Ks[(t * 16 + r) * PKA + (g & 1) * 8];
            sacc[t] = __builtin_amdgcn_mfma_f32_16x16x32_bf16(aq, bk_, (f32x4)0.f, 0, 0, 0);
        }

        if (mt + 4 < 25) loadq(mt + 4);

        float lv[4];
        #pragma unroll
        for (int i = 0; i < 4; i++) {
            float tm[16];
            #pragma unroll
            for (int t = 0; t < 9; t++) tm[t] = fmaxf(sacc[t][i], sacc[t + 16][i]);
            #pragma unroll
            for (int t = 9; t < 16; t++) tm[t] = sacc[t][i];
            #pragma unroll
            for (int off = 8; off; off >>= 1)
                #pragma unroll
                for (int t = 0; t < off; t++) tm[t] = fmaxf(tm[t], tm[t + off]);
            float m_ = tm[0];
            #pragma unroll
            for (int off = 8; off; off >>= 1) m_ = fmaxf(m_, __shfl_xor(m_, off, 16));

            #pragma unroll
            for (int t = 0; t < 25; t++) sacc[t][i] = __expf(sacc[t][i] - m_);

            float ts[16];
            #pragma unroll
            for (int t = 0; t < 9; t++) ts[t] = sacc[t][i] + sacc[t + 16][i];
            #pragma unroll
            for (int t = 9; t < 16; t++) ts[t] = sacc[t][i];
            #pragma unroll
            for (int off = 8; off; off >>= 1)
                #pragma unroll
                for (int t = 0; t < off; t++) ts[t] += ts[t + off];
            float l_ = ts[0];
            #pragma unroll
            for (int off = 8; off; off >>= 1) l_ += __shfl_xor(l_, off, 16);
            lv[i] = l_;
        }

        f32x4 oacc = (f32x4)0.f;

        #pragma unroll
        for (int t = 0; t < 13; t++)
            #pragma unroll
            for (int i = 0; i < 4; i++)
                Pw[(g * 4 + i) * PPA + t * 16 + r] = (__bf16)sacc[t][i];
        __asm__ volatile("s_waitcnt lgkmcnt(0)" ::: "memory");
        #pragma unroll
        for (int c = 0; c < 7; c++) {
            bf16x8 ap  = *(const bf16x8*)&Pw[r * PPA + c * 32 + g * 8];
            bf16x8 bv_ = *(const bf16x8*)&Vt[r * PVA + c * 32 + g * 8];
            oacc = __builtin_amdgcn_mfma_f32_16x16x32_bf16(ap, bv_, oacc, 0, 0, 0);
        }

        #pragma unroll
        for (int t = 13; t < 25; t++)
            #pragma unroll
            for (int i = 0; i < 4; i++)
                Pw[(g * 4 + i) * PPA + (t - 13) * 16 + r] = (__bf16)sacc[t][i];
        __asm__ volatile("s_waitcnt lgkmcnt(0)" ::: "memory");
        #pragma unroll
        for (int c = 0; c < 6; c++) {
            bf16x8 ap  = *(const bf16x8*)&Pw[r * PPA + c * 32 + g * 8];
            bf16x8 bv_ = *(const bf16x8*)&Vt[r * PVA + 208 + c * 32 + g * 8];
            oacc = __builtin_amdgcn_mfma_f32_16x16x32_bf16(ap, bv_, oacc, 0, 0, 0);
        }

        #pragma unroll
        for (int i = 0; i < 4; i++) {
            float rl = __builtin_amdgcn_rcpf(lv[i]);
            oT[((size_t)(m0 + g * 4 + i) * BATCH + b) * ADIMM + h * HEADD + r] = oacc[i] * rl;
        }
    }
}

// ---------------------------------------------------------------------------
// Kernel D: attended = h3 + o*Wo + bo (MFMA); logits = attended*Wout[a]+bout.
// (exact 356.8-us build: h3 prefetch at top, Wout staged to LDS)
// ---------------------------------------------------------------------------
__global__ __launch_bounds__(256, 2) void out_kernel(
    const float* __restrict__ h3, const float* __restrict__ oT,
    const float* __restrict__ Wo, const float* __restrict__ bo,
    const float* __restrict__ Wout, const float* __restrict__ bout,
    float* __restrict__ out)
{
    const int a    = blockIdx.x;
    const int tid  = threadIdx.x;
    const int wave = tid >> 6, lane = tid & 63;
    const int r = lane & 15, g = lane >> 4;
    const int n0 = 48 * wave;

    __shared__ __align__(16) __bf16 os[64 * POUT];
    __shared__ __align__(16) __bf16 att[64 * PA];
    __shared__ __align__(16) float  wout_s[HDIM * ODIM];

    float h3v[3][4][4];
    #pragma unroll
    for (int t = 0; t < 3; t++) {
        int col = n0 + 16 * t + r;
        #pragma unroll
        for (int rg = 0; rg < 4; rg++)
            #pragma unroll
            for (int i = 0; i < 4; i++)
                h3v[t][rg][i] = h3[((size_t)a * BATCH + 16 * rg + 4 * g + i) * HDIM + col];
    }

    for (int idx = tid; idx < 64 * 32; idx += 256) {
        int bb = idx >> 5, q = idx & 31;
        float4 v = ((const float4*)(oT + ((size_t)a * BATCH + bb) * ADIMM))[q];
        unsigned u0 = pack_bf16x2(v.x, v.y);
        unsigned u1 = pack_bf16x2(v.z, v.w);
        *(uint2*)&os[bb * POUT + q * 4] = make_uint2(u0, u1);
    }
    {
        const float4* src = (const float4*)(Wout + (size_t)a * HDIM * ODIM);
        for (int idx = tid; idx < HDIM * ODIM / 4; idx += 256)
            ((float4*)wout_s)[idx] = src[idx];
    }
    __syncthreads();

    {
        const float* wA[3] = { Wo + n0, Wo + n0 + 16, Wo + n0 + 32 };
        f32x4 acc[4][3];
        #pragma unroll
        for (int i = 0; i < 4; i++)
            #pragma unroll
            for (int t = 0; t < 3; t++) acc[i][t] = (f32x4)0.f;
        gemm_bpass<4, ADIMM, 3, 4, HDIM, POUT>(acc, wA, os, lane);
        #pragma unroll
        for (int t = 0; t < 3; t++) {
            int col = n0 + 16 * t + r;
            float bb = bo[col];
            #pragma unroll
            for (int rg = 0; rg < 4; rg++)
                #pragma unroll
                for (int i = 0; i < 4; i++) {
                    int row = 16 * rg + 4 * g + i;
                    float v = h3v[t][rg][i] + acc[rg][t][i] + bb;
                    att[row * PA + col] = (__bf16)v;
                }
        }
    }
    __syncthreads();

    {
        float wb[48];
        #pragma unroll
        for (int c = 0; c < 6; c++)
            #pragma unroll
            for (int j = 0; j < 8; j++) {
                int k = c * 32 + g * 8 + j;
                wb[c * 8 + j] = (r < ODIM) ? wout_s[k * ODIM + r] : 0.f;
            }
        f32x4 oacc = (f32x4)0.f;
        #pragma unroll
        for (int c = 0; c < 6; c++) {
            bf16x8 bf;
            #pragma unroll
            for (int j = 0; j < 8; j++) bf[j] = (__bf16)wb[c * 8 + j];
            bf16x8 af = *(const bf16x8*)&att[(16 * wave + r) * PA + c * 32 + g * 8];
            oacc = __builtin_amdgcn_mfma_f32_16x16x32_bf16(af, bf, oacc, 0, 0, 0);
        }
        if (r < ODIM) {
            float bb = bout[a * ODIM + r];
            #pragma unroll
            for (int i = 0; i < 4; i++) {
                int row = 16 * wave + 4 * g + i;
                out[((size_t)a * BATCH + row) * ODIM + r] = oacc[i] + bb;
            }
        }
    }
}

// ---------------------------------------------------------------------------
extern "C" void kernel_launch(void* const* d_in, const int* in_sizes, int n_in,
                              void* d_out, int out_size, void* d_ws, size_t ws_size,
                              hipStream_t stream)
{
    const float* x       = (const float*)d_in[0];
    const float* ln_in_g = (const float*)d_in[1];
    const float* ln_in_b = (const float*)d_in[2];
    const float* W1      = (const float*)d_in[3];
    const float* b1      = (const float*)d_in[4];
    const float* Ws1     = (const float*)d_in[5];
    const float* bs1     = (const float*)d_in[6];
    const float* W2      = (const float*)d_in[7];
    const float* b2      = (const float*)d_in[8];
    const float* Ws2     = (const float*)d_in[9];
    const float* bs2     = (const float*)d_in[10];
    const float* W3      = (const float*)d_in[11];
    const float* b3      = (const float*)d_in[12];
    const float* ln_h_g  = (const float*)d_in[13];
    const float* ln_h_b  = (const float*)d_in[14];
    const float* Wout    = (const float*)d_in[15];
    const float* bout    = (const float*)d_in[16];
    const float* aln_g   = (const float*)d_in[17];
    const float* aln_b   = (const float*)d_in[18];
    const float* Wq      = (const float*)d_in[19];
    const float* bq      = (const float*)d_in[20];
    const float* Wk      = (const float*)d_in[21];
    const float* bk      = (const float*)d_in[22];
    const float* Wv      = (const float*)d_in[23];
    const float* bv      = (const float*)d_in[24];
    const float* Wo      = (const float*)d_in[25];
    const float* bo      = (const float*)d_in[26];
    float* out = (float*)d_out;

    float* ws = (float*)d_ws;
    const size_t H3_SZ = (size_t)AGENTS * BATCH * HDIM;
    const size_t QT_SZ = (size_t)BATCH * NHEADS * AGENTS * HEADD;
    float* h3 = ws;
    float* qT = h3 + H3_SZ;
    float* kT = qT + QT_SZ;
    float* vT = kT + QT_SZ;
    float* oT = vT + QT_SZ;

    mlp_kernel<<<AGENTS * 2, 256, 0, stream>>>(x, ln_in_g, ln_in_b,
                                               W1, b1, Ws1, bs1, W2, b2, Ws2, bs2,
                                               W3, b3, ln_h_g, ln_h_b,
                                               aln_g, aln_b, Wq, bq, Wk, bk, Wv, bv,
                                               h3, qT, kT, vT);
    attn_kernel<<<BATCH * NHEADS, 256, 0, stream>>>(qT, kT, vT, oT);
    out_kernel<<<AGENTS, 256, 0, stream>>>(h3, oT, Wo, bo, Wout, bout, out);
}

// Round 9
// 354.629 us; speedup vs baseline: 1.0625x; 1.0272x over previous
//
#include <hip/hip_runtime.h>
#include <math.h>

#define AGENTS 400
#define BATCH  64
#define IDIM   50
#define HDIM   192
#define ODIM   3
#define ADIMM  128
#define NHEADS 8
#define HEADD  16
#define LN_EPS 1e-5f

#define PA   200  // activation LDS pitch in bf16 for qkv/out kernels (16B-aligned rows)
#define PAM  192  // mlp activation pitch (384B rows; banking handled by XOR swizzle)
#define POUT 136  // o LDS pitch in bf16 (272 B rows, 16B-aligned)

typedef __bf16 bf16x8 __attribute__((ext_vector_type(8)));
typedef float  f32x4  __attribute__((ext_vector_type(4)));

__device__ __forceinline__ float gelu_exact(float x) {
    return 0.5f * x * (1.0f + erff(x * 0.70710678118654752f));
}

__device__ __forceinline__ unsigned pack_bf16x2(float a, float b) {
    unsigned short ua = __builtin_bit_cast(unsigned short, (__bf16)a);
    unsigned short ub = __builtin_bit_cast(unsigned short, (__bf16)b);
    return (unsigned)ua | ((unsigned)ub << 16);
}

// ---------------------------------------------------------------------------
// Swizzled As accessors (mlp kernel).  8-element bf16 blocks XOR'd with row&7
// so strided fragment reads spread across all 32 banks.
// ---------------------------------------------------------------------------
__device__ __forceinline__ int as_swz(int row, int col) {
    return ((((col >> 3) ^ (row & 7)) << 3) | (col & 7));
}
__device__ __forceinline__ void st_as(__bf16* As_, int row, int col, float v) {
    As_[row * PAM + as_swz(row, col)] = (__bf16)v;
}
__device__ __forceinline__ float ld_as(const __bf16* As_, int row, int col) {
    return (float)As_[row * PAM + as_swz(row, col)];
}
__device__ __forceinline__ bf16x8 ld_afrag(const __bf16* As_, int row, int k0) {
    int blk = (((k0 >> 3) ^ (row & 7)) << 3);
    return *(const bf16x8*)&As_[row * PAM + blk];
}

// ---------------------------------------------------------------------------
// Pipeline sync primitives (R3-verified schedule: issue(next); compute(cur);
// vmcnt(0); s_barrier -- nothing outstanding ever crosses a raw barrier).
// ---------------------------------------------------------------------------
#define VMWAIT0()   do { asm volatile("s_waitcnt vmcnt(0)" ::: "memory"); \
                         __builtin_amdgcn_sched_barrier(0); } while (0)
#define BARRIER()   do { __builtin_amdgcn_s_barrier(); \
                         __builtin_amdgcn_sched_barrier(0); } while (0)

struct WPtrs { const float *W1, *Ws1, *W2, *Ws2, *W3; };

// ---------------------------------------------------------------------------
// Issue one K=32 weight chunk (32 x 192 f32 = 24 KB) as 6 async
// global_load_lds dwordx4 per thread.  LDS dest is linear; the global SOURCE
// column is pre-swizzled (n' = n ^ (k_octet<<3)) so the B-fragment
// ds_read_b32 pattern is 2-way banked.  Slot order:
// [W1c0 Ws1c0 W1c1 Ws1c1 | W2c0 Ws2c0 .. Ws2c5 | W3c0..W3c5].
// ---------------------------------------------------------------------------
__device__ __forceinline__ void issue_slot(int s, float* buf0, float* buf1,
                                           const WPtrs& P, const int* kloc,
                                           const int* nsw, int tid)
{
    const float* M; int c, kdm1;
    if (s < 4)       { M = (s & 1) ? P.Ws1 : P.W1; c = s >> 1;      kdm1 = IDIM - 1; }
    else if (s < 16) { int u = s - 4; M = (u & 1) ? P.Ws2 : P.W2; c = u >> 1; kdm1 = HDIM - 1; }
    else             { M = P.W3; c = s - 16; kdm1 = HDIM - 1; }
    float* dst = (s & 1) ? buf1 : buf0;
    #pragma unroll
    for (int i = 0; i < 6; i++) {
        int kg = c * 32 + kloc[i];
        kg = (kg <= kdm1) ? kg : kdm1;
        const float* src = M + (size_t)kg * HDIM + nsw[i];
        __builtin_amdgcn_global_load_lds(
            (const __attribute__((address_space(1))) void*)src,
            (__attribute__((address_space(3))) void*)(dst + (i * 256 + tid) * 4),
            16, 0, 0);
    }
    __builtin_amdgcn_sched_barrier(0);
}

// ---------------------------------------------------------------------------
// One MFMA slot from an f32 LDS weight chunk: build 3 B-frags (24 ds_read_b32,
// swizzled columns, 2-way banked) + 4 A-frags, 12 MFMAs.
// ---------------------------------------------------------------------------
__device__ __forceinline__ void slot_mfma_f32(f32x4 (&acc)[4][3], const __bf16* As_,
                                              const float* Wbuf, int c, int n0, int lane)
{
    const int r = lane & 15, g = lane >> 4;
    bf16x8 bf[3];
    #pragma unroll
    for (int t = 0; t < 3; t++) {
        int cs = (n0 + 16 * t + r) ^ (g << 3);   // undo source pre-swizzle
        #pragma unroll
        for (int j = 0; j < 8; j++)
            bf[t][j] = (__bf16)Wbuf[(g * 8 + j) * HDIM + cs];
    }
    #pragma unroll
    for (int rg = 0; rg < 4; rg++) {
        bf16x8 af = ld_afrag(As_, 16 * rg + r, c * 32 + g * 8);
        #pragma unroll
        for (int t = 0; t < 3; t++)
            acc[rg][t] = __builtin_amdgcn_mfma_f32_16x16x32_bf16(af, bf[t], acc[rg][t], 0, 0, 0);
    }
}

// ---------------------------------------------------------------------------
// Kernel A: per-agent MLP (R3-verified 101-us build).  One block (4 waves)
// per agent.  Weight chunks stream through a double-buffered LDS ring via
// async global_load_lds; per-slot schedule: issue(next); compute(cur);
// vmcnt(0); s_barrier.  Activations stay in swizzled LDS.
// ---------------------------------------------------------------------------
__global__ __launch_bounds__(256, 2) void mlp_kernel(
    const float* __restrict__ x,
    const float* __restrict__ ln_in_g, const float* __restrict__ ln_in_b,
    const float* __restrict__ W1, const float* __restrict__ b1,
    const float* __restrict__ Ws1, const float* __restrict__ bs1,
    const float* __restrict__ W2, const float* __restrict__ b2,
    const float* __restrict__ Ws2, const float* __restrict__ bs2,
    const float* __restrict__ W3, const float* __restrict__ b3,
    const float* __restrict__ ln_h_g, const float* __restrict__ ln_h_b,
    float* __restrict__ h3out)
{
    const int a    = blockIdx.x;
    const int tid  = threadIdx.x;
    const int wave = tid >> 6, lane = tid & 63;
    const int r = lane & 15, g = lane >> 4;
    const int n0 = 48 * wave;

    __shared__ __align__(16) __bf16 As[64 * PAM];        // 24.6 KB
    __shared__ __align__(16) float  Wbuf[2][32 * HDIM];  // 48 KB ring
    __shared__ float mu_s[64], rs_s[64];

    int kloc[6], nsw[6];
    #pragma unroll
    for (int i = 0; i < 6; i++) {
        int w = i * 1024 + tid * 4;
        kloc[i] = w / HDIM;
        int np = w - kloc[i] * HDIM;
        nsw[i] = np ^ (((kloc[i] >> 3) & 3) << 3);
    }

    const WPtrs P = {
        W1  + (size_t)a * IDIM * HDIM,
        Ws1 + (size_t)a * IDIM * HDIM,
        W2  + (size_t)a * HDIM * HDIM,
        Ws2 + (size_t)a * HDIM * HDIM,
        W3  + (size_t)a * HDIM * HDIM };

    // ---- input LN: stats on raw x rows (shared), per-agent affine ----
    {
        int rr = tid >> 2, l = tid & 3;
        float s = 0.f, ss = 0.f;
        for (int k = l; k < IDIM; k += 4) { float v = x[rr * IDIM + k]; s += v; ss += v * v; }
        s  += __shfl_down(s, 2, 4);  s  += __shfl_down(s, 1, 4);
        ss += __shfl_down(ss, 2, 4); ss += __shfl_down(ss, 1, 4);
        if (l == 0) {
            float mu = s * (1.0f / IDIM);
            float var = ss * (1.0f / IDIM) - mu * mu;
            mu_s[rr] = mu;
            rs_s[rr] = rsqrtf(var + LN_EPS);
        }
    }
    __syncthreads();

    issue_slot(0, Wbuf[0], Wbuf[1], P, kloc, nsw, tid);  // hides under As fill

    for (int sidx = tid; sidx < 64 * 64; sidx += 256) {
        int rr = sidx >> 6, k = sidx & 63;
        float v = 0.f;
        if (k < IDIM)
            v = (x[rr * IDIM + k] - mu_s[rr]) * rs_s[rr] * ln_in_g[a * IDIM + k] + ln_in_b[a * IDIM + k];
        st_as(As, rr, k, v);   // zero-pad k in [IDIM,64)
    }
    __syncthreads();           // drains vmcnt: slot 0 resident for all waves

    // ======== stage 1: h1 = gelu(xn*W1+b1) + xn*Ws1+bs1  (slots 0-3) ======
    {
        f32x4 acc1[4][3], acc2[4][3];
        #pragma unroll
        for (int i = 0; i < 4; i++)
            #pragma unroll
            for (int t = 0; t < 3; t++) { acc1[i][t] = (f32x4)0.f; acc2[i][t] = (f32x4)0.f; }
        #pragma unroll
        for (int s = 0; s < 4; s++) {
            if (s < 3) issue_slot(s + 1, Wbuf[0], Wbuf[1], P, kloc, nsw, tid);
            if ((s & 1) == 0) slot_mfma_f32(acc1, As, Wbuf[s & 1], s >> 1, n0, lane);
            else              slot_mfma_f32(acc2, As, Wbuf[s & 1], s >> 1, n0, lane);
            VMWAIT0();
            BARRIER();
        }
        issue_slot(4, Wbuf[0], Wbuf[1], P, kloc, nsw, tid);   // lands under epilogue
        #pragma unroll
        for (int t = 0; t < 3; t++) {
            int col = n0 + 16 * t + r;
            float bb  = b1[a * HDIM + col];
            float bbs = bs1[a * HDIM + col];
            #pragma unroll
            for (int rg = 0; rg < 4; rg++)
                #pragma unroll
                for (int i = 0; i < 4; i++) {
                    int row = 16 * rg + 4 * g + i;
                    st_as(As, row, col, gelu_exact(acc1[rg][t][i] + bb) + acc2[rg][t][i] + bbs);
                }
        }
        __syncthreads();     // h1 visible; slot 4 resident
    }

    // ======== stage 2: h2 = gelu(h1*W2+b2) + h1*Ws2+bs2  (slots 4-15) =====
    {
        f32x4 acc1[4][3], acc2[4][3];
        #pragma unroll
        for (int i = 0; i < 4; i++)
            #pragma unroll
            for (int t = 0; t < 3; t++) { acc1[i][t] = (f32x4)0.f; acc2[i][t] = (f32x4)0.f; }
        #pragma unroll
        for (int s = 4; s < 16; s++) {
            if (s < 15) issue_slot(s + 1, Wbuf[0], Wbuf[1], P, kloc, nsw, tid);
            if ((s & 1) == 0) slot_mfma_f32(acc1, As, Wbuf[s & 1], (s - 4) >> 1, n0, lane);
            else              slot_mfma_f32(acc2, As, Wbuf[s & 1], (s - 4) >> 1, n0, lane);
            VMWAIT0();
            BARRIER();
        }
        issue_slot(16, Wbuf[0], Wbuf[1], P, kloc, nsw, tid);  // lands under epilogue
        #pragma unroll
        for (int t = 0; t < 3; t++) {
            int col = n0 + 16 * t + r;
            float bb  = b2[a * HDIM + col];
            float bbs = bs2[a * HDIM + col];
            #pragma unroll
            for (int rg = 0; rg < 4; rg++)
                #pragma unroll
                for (int i = 0; i < 4; i++) {
                    int row = 16 * rg + 4 * g + i;
                    st_as(As, row, col, gelu_exact(acc1[rg][t][i] + bb) + acc2[rg][t][i] + bbs);
                }
        }
        __syncthreads();     // h2 visible; slot 16 resident
    }

    // ======== stage 3: t = h2 + h2*W3 + b3 (slots 16-21), then LN =========
    {
        f32x4 acc[4][3];
        #pragma unroll
        for (int i = 0; i < 4; i++)
            #pragma unroll
            for (int t = 0; t < 3; t++) acc[i][t] = (f32x4)0.f;
        #pragma unroll
        for (int s = 16; s < 22; s++) {
            if (s < 21) issue_slot(s + 1, Wbuf[0], Wbuf[1], P, kloc, nsw, tid);
            slot_mfma_f32(acc, As, Wbuf[s & 1], s - 16, n0, lane);
            VMWAIT0();
            BARRIER();
        }
        #pragma unroll
        for (int t = 0; t < 3; t++) {
            int col = n0 + 16 * t + r;
            float bb = b3[a * HDIM + col];
            #pragma unroll
            for (int rg = 0; rg < 4; rg++)
                #pragma unroll
                for (int i = 0; i < 4; i++) {
                    int row = 16 * rg + 4 * g + i;
                    st_as(As, row, col, ld_as(As, row, col) + acc[rg][t][i] + bb);
                }
        }
        __syncthreads();
    }

    // ---- hidden LN (per-agent affine) -> h3out ----
    {
        int rr = tid >> 2, l = tid & 3;
        float s = 0.f, ss = 0.f;
        for (int k = l; k < HDIM; k += 4) { float v = ld_as(As, rr, k); s += v; ss += v * v; }
        s  += __shfl_down(s, 2, 4);  s  += __shfl_down(s, 1, 4);
        ss += __shfl_down(ss, 2, 4); ss += __shfl_down(ss, 1, 4);
        if (l == 0) {
            float mu = s * (1.0f / HDIM);
            float var = ss * (1.0f / HDIM) - mu * mu;
            mu_s[rr] = mu;
            rs_s[rr] = rsqrtf(var + LN_EPS);
        }
    }
    __syncthreads();
    for (int sidx = tid; sidx < 64 * 48; sidx += 256) {   // float4-vectorized write
        int rr = sidx / 48, q = sidx - rr * 48;
        int c = q * 4;                                     // c%8 in {0,4}: one swizzle block
        const __bf16* p = &As[rr * PAM + as_swz(rr, c)];
        float4 gv = *(const float4*)&ln_h_g[a * HDIM + c];
        float4 bv = *(const float4*)&ln_h_b[a * HDIM + c];
        float mu = mu_s[rr], rs = rs_s[rr];
        float4 o;
        o.x = ((float)p[0] - mu) * rs * gv.x + bv.x;
        o.y = ((float)p[1] - mu) * rs * gv.y + bv.y;
        o.z = ((float)p[2] - mu) * rs * gv.z + bv.z;
        o.w = ((float)p[3] - mu) * rs * gv.w + bv.w;
        *(float4*)&h3out[((size_t)a * BATCH + rr) * HDIM + c] = o;
    }
}

// ---------------------------------------------------------------------------
// Register-staged GEMM pass (for the small shared-weight GEMMs: qkv, out).
// ---------------------------------------------------------------------------
template<int NC, int KD, int NT, int NRG, int LDW, int PITCH>
__device__ __forceinline__ void gemm_bpass(f32x4 (&acc)[NRG][NT],
                                           const float* const* wptr,
                                           const __bf16* Asrc, int lane)
{
    const int r = lane & 15, g = lane >> 4;
    float buf[2][NT * 8];

    #pragma unroll
    for (int t = 0; t < NT; t++)
        #pragma unroll
        for (int j = 0; j < 8; j++) {
            int k = g * 8 + j;
            buf[0][t * 8 + j] = (k < KD) ? wptr[t][k * LDW + r] : 0.f;
        }

    #pragma unroll
    for (int c = 0; c < NC; c++) {
        const int cur = c & 1, nxt = cur ^ 1;
        if (c + 1 < NC) {
            #pragma unroll
            for (int t = 0; t < NT; t++)
                #pragma unroll
                for (int j = 0; j < 8; j++) {
                    int k = (c + 1) * 32 + g * 8 + j;
                    buf[nxt][t * 8 + j] = (k < KD) ? wptr[t][k * LDW + r] : 0.f;
                }
        }
        bf16x8 bfr[NT];
        #pragma unroll
        for (int t = 0; t < NT; t++)
            #pragma unroll
            for (int j = 0; j < 8; j++)
                bfr[t][j] = (__bf16)buf[cur][t * 8 + j];
        #pragma unroll
        for (int rg = 0; rg < NRG; rg++) {
            bf16x8 af = *(const bf16x8*)&Asrc[(16 * rg + r) * PITCH + c * 32 + g * 8];
            #pragma unroll
            for (int t = 0; t < NT; t++)
                acc[rg][t] = __builtin_amdgcn_mfma_f32_16x16x32_bf16(af, bfr[t], acc[rg][t], 0, 0, 0);
        }
    }
}

// ---------------------------------------------------------------------------
// Kernel B: y = LN(h3, shared affine); fused Q|K|V GEMM on MFMA.
// (standalone R3-verified ~29-us build)
// ---------------------------------------------------------------------------
__global__ __launch_bounds__(256, 2) void qkv_kernel(
    const float* __restrict__ h3,
    const float* __restrict__ aln_g, const float* __restrict__ aln_b,
    const float* __restrict__ Wq, const float* __restrict__ bq,
    const float* __restrict__ Wk, const float* __restrict__ bk,
    const float* __restrict__ Wv, const float* __restrict__ bv,
    float* __restrict__ qT, float* __restrict__ kT, float* __restrict__ vT)
{
    const int a    = blockIdx.x;
    const int tid  = threadIdx.x;
    const int wave = tid >> 6, lane = tid & 63;
    const int r = lane & 15, g = lane >> 4;

    __shared__ __align__(16) __bf16 ys[64 * PA];
    __shared__ float mu_s[64], rs_s[64];

    {
        int rr = tid >> 2, l = tid & 3;
        const float* hp = h3 + ((size_t)a * BATCH + rr) * HDIM;
        float s = 0.f, ss = 0.f;
        for (int k = l; k < HDIM; k += 4) { float v = hp[k]; s += v; ss += v * v; }
        s  += __shfl_down(s, 2, 4);  s  += __shfl_down(s, 1, 4);
        ss += __shfl_down(ss, 2, 4); ss += __shfl_down(ss, 1, 4);
        if (l == 0) {
            float mu = s * (1.0f / HDIM);
            float var = ss * (1.0f / HDIM) - mu * mu;
            mu_s[rr] = mu;
            rs_s[rr] = rsqrtf(var + LN_EPS);
        }
    }
    __syncthreads();
    for (int sidx = tid; sidx < 64 * HDIM; sidx += 256) {
        int rr = sidx / HDIM, c = sidx - rr * HDIM;
        float v = (h3[((size_t)a * BATCH + rr) * HDIM + c] - mu_s[rr]) * rs_s[rr] * aln_g[c] + aln_b[c];
        ys[rr * PA + c] = (__bf16)v;
    }
    __syncthreads();

    #pragma unroll
    for (int p = 0; p < 2; p++) {
        const int nb = 192 * p + 48 * wave;
        const float* wA[3];
        #pragma unroll
        for (int t = 0; t < 3; t++) {
            int nt = nb + 16 * t;
            const float* base = (nt < 128) ? Wq : (nt < 256) ? Wk : Wv;
            wA[t] = base + (nt & 127);
        }
        f32x4 acc[4][3];
        #pragma unroll
        for (int i = 0; i < 4; i++)
            #pragma unroll
            for (int t = 0; t < 3; t++) acc[i][t] = (f32x4)0.f;
        gemm_bpass<6, HDIM, 3, 4, ADIMM, PA>(acc, wA, ys, lane);

        #pragma unroll
        for (int t = 0; t < 3; t++) {
            int n = nb + 16 * t + r;
            int which = n >> 7, cc = n & 127, hh = cc >> 4, dd = cc & 15;
            const float* bp = (which == 0) ? bq : (which == 1) ? bk : bv;
            float* op = (which == 0) ? qT : (which == 1) ? kT : vT;
            float bb = bp[cc];
            #pragma unroll
            for (int rg = 0; rg < 4; rg++)
                #pragma unroll
                for (int i = 0; i < 4; i++) {
                    int brow = 16 * rg + 4 * g + i;
                    op[(((size_t)brow * NHEADS + hh) * AGENTS + a) * HEADD + dd] = acc[rg][t][i] + bb;
                }
        }
    }
}

// ---------------------------------------------------------------------------
// Kernel C: cross-agent attention on MFMA.  One block (4 waves) per (b,h).
// (R6-verified build: float4 K/V staging, Q double-buffer, tree reductions,
// rcp epilogue)
// ---------------------------------------------------------------------------
#define PKA 24
#define PVA 408
#define PPA 232

__global__ __launch_bounds__(256, 2) void attn_kernel(
    const float* __restrict__ qT, const float* __restrict__ kT,
    const float* __restrict__ vT, float* __restrict__ oT)
{
    const int bh   = blockIdx.x;
    const int b    = bh >> 3, h = bh & 7;
    const int tid  = threadIdx.x;
    const int wave = tid >> 6, lane = tid & 63;
    const int r = lane & 15, g = lane >> 4;

    __shared__ __align__(16) __bf16 Ks[AGENTS * PKA];
    __shared__ __align__(16) __bf16 Vt[16 * PVA];
    __shared__ __align__(16) __bf16 Ps[4][16 * PPA];

    const float* kp = kT + (size_t)bh * AGENTS * HEADD;
    const float* vp = vT + (size_t)bh * AGENTS * HEADD;
    for (int idx4 = tid; idx4 < AGENTS * HEADD / 4; idx4 += 256) {
        int a_ = idx4 >> 2, d0 = (idx4 & 3) << 2;
        float4 kv = *(const float4*)(kp + a_ * HEADD + d0);
        float4 vv = *(const float4*)(vp + a_ * HEADD + d0);
        *(uint2*)&Ks[a_ * PKA + d0] =
            make_uint2(pack_bf16x2(kv.x, kv.y), pack_bf16x2(kv.z, kv.w));
        Vt[(d0 + 0) * PVA + a_] = (__bf16)vv.x;
        Vt[(d0 + 1) * PVA + a_] = (__bf16)vv.y;
        Vt[(d0 + 2) * PVA + a_] = (__bf16)vv.z;
        Vt[(d0 + 3) * PVA + a_] = (__bf16)vv.w;
    }
    __bf16* Pw = Ps[wave];
    for (int z = lane; z < 16 * 16; z += 64)
        Pw[(z >> 4) * PPA + 208 + (z & 15)] = (__bf16)0.f;
    __syncthreads();

    float qf[8];
    auto loadq = [&](int mt_) {
        if (g < 2) {
            const float* qp = qT + ((size_t)bh * AGENTS + mt_ * 16 + r) * HEADD + g * 8;
            float4 v0 = *(const float4*)qp;
            float4 v1 = *(const float4*)(qp + 4);
            qf[0] = v0.x; qf[1] = v0.y; qf[2] = v0.z; qf[3] = v0.w;
            qf[4] = v1.x; qf[5] = v1.y; qf[6] = v1.z; qf[7] = v1.w;
        }
    };
    loadq(wave);

    for (int mt = wave; mt < 25; mt += 4) {
        const int m0 = mt * 16;

        bf16x8 aq;
        #pragma unroll
        for (int j = 0; j < 8; j++)
            aq[j] = (g < 2) ? (__bf16)(qf[j] * 0.25f) : (__bf16)0.f;

        f32x4 sacc[25];
        #pragma unroll
        for (int t = 0; t < 25; t++) {
            bf16x8 bk_ = *(const bf16x8*)&Ks[(t * 16 + r) * PKA + (g & 1) * 8];
            sacc[t] = __builtin_amdgcn_mfma_f32_16x16x32_bf16(aq, bk_, (f32x4)0.f, 0, 0, 0);
        }

        if (mt + 4 < 25) loadq(mt + 4);

        float lv[4];
        #pragma unroll
        for (int i = 0; i < 4; i++) {
            float tm[16];
            #pragma unroll
            for (int t = 0; t < 9; t++) tm[t] = fmaxf(sacc[t][i], sacc[t + 16][i]);
            #pragma unroll
            for (int t = 9; t < 16; t++) tm[t] = sacc[t][i];
            #pragma unroll
            for (int off = 8; off; off >>= 1)
                #pragma unroll
                for (int t = 0; t < off; t++) tm[t] = fmaxf(tm[t], tm[t + off]);
            float m_ = tm[0];
            #pragma unroll
            for (int off = 8; off; off >>= 1) m_ = fmaxf(m_, __shfl_xor(m_, off, 16));

            #pragma unroll
            for (int t = 0; t < 25; t++) sacc[t][i] = __expf(sacc[t][i] - m_);

            float ts[16];
            #pragma unroll
            for (int t = 0; t < 9; t++) ts[t] = sacc[t][i] + sacc[t + 16][i];
            #pragma unroll
            for (int t = 9; t < 16; t++) ts[t] = sacc[t][i];
            #pragma unroll
            for (int off = 8; off; off >>= 1)
                #pragma unroll
                for (int t = 0; t < off; t++) ts[t] += ts[t + off];
            float l_ = ts[0];
            #pragma unroll
            for (int off = 8; off; off >>= 1) l_ += __shfl_xor(l_, off, 16);
            lv[i] = l_;
        }

        f32x4 oacc = (f32x4)0.f;

        #pragma unroll
        for (int t = 0; t < 13; t++)
            #pragma unroll
            for (int i = 0; i < 4; i++)
                Pw[(g * 4 + i) * PPA + t * 16 + r] = (__bf16)sacc[t][i];
        __asm__ volatile("s_waitcnt lgkmcnt(0)" ::: "memory");
        #pragma unroll
        for (int c = 0; c < 7; c++) {
            bf16x8 ap  = *(const bf16x8*)&Pw[r * PPA + c * 32 + g * 8];
            bf16x8 bv_ = *(const bf16x8*)&Vt[r * PVA + c * 32 + g * 8];
            oacc = __builtin_amdgcn_mfma_f32_16x16x32_bf16(ap, bv_, oacc, 0, 0, 0);
        }

        #pragma unroll
        for (int t = 13; t < 25; t++)
            #pragma unroll
            for (int i = 0; i < 4; i++)
                Pw[(g * 4 + i) * PPA + (t - 13) * 16 + r] = (__bf16)sacc[t][i];
        __asm__ volatile("s_waitcnt lgkmcnt(0)" ::: "memory");
        #pragma unroll
        for (int c = 0; c < 6; c++) {
            bf16x8 ap  = *(const bf16x8*)&Pw[r * PPA + c * 32 + g * 8];
            bf16x8 bv_ = *(const bf16x8*)&Vt[r * PVA + 208 + c * 32 + g * 8];
            oacc = __builtin_amdgcn_mfma_f32_16x16x32_bf16(ap, bv_, oacc, 0, 0, 0);
        }

        #pragma unroll
        for (int i = 0; i < 4; i++) {
            float rl = __builtin_amdgcn_rcpf(lv[i]);
            oT[((size_t)(m0 + g * 4 + i) * BATCH + b) * ADIMM + h * HEADD + r] = oacc[i] * rl;
        }
    }
}

// ---------------------------------------------------------------------------
// Kernel D: attended = h3 + o*Wo + bo (MFMA); logits = attended*Wout[a]+bout.
// (R6-verified build: h3 prefetch at top, Wout staged to LDS)
// ---------------------------------------------------------------------------
__global__ __launch_bounds__(256, 2) void out_kernel(
    const float* __restrict__ h3, const float* __restrict__ oT,
    const float* __restrict__ Wo, const float* __restrict__ bo,
    const float* __restrict__ Wout, const float* __restrict__ bout,
    float* __restrict__ out)
{
    const int a    = blockIdx.x;
    const int tid  = threadIdx.x;
    const int wave = tid >> 6, lane = tid & 63;
    const int r = lane & 15, g = lane >> 4;
    const int n0 = 48 * wave;

    __shared__ __align__(16) __bf16 os[64 * POUT];
    __shared__ __align__(16) __bf16 att[64 * PA];
    __shared__ __align__(16) float  wout_s[HDIM * ODIM];

    float h3v[3][4][4];
    #pragma unroll
    for (int t = 0; t < 3; t++) {
        int col = n0 + 16 * t + r;
        #pragma unroll
        for (int rg = 0; rg < 4; rg++)
            #pragma unroll
            for (int i = 0; i < 4; i++)
                h3v[t][rg][i] = h3[((size_t)a * BATCH + 16 * rg + 4 * g + i) * HDIM + col];
    }

    for (int idx = tid; idx < 64 * 32; idx += 256) {
        int bb = idx >> 5, q = idx & 31;
        float4 v = ((const float4*)(oT + ((size_t)a * BATCH + bb) * ADIMM))[q];
        unsigned u0 = pack_bf16x2(v.x, v.y);
        unsigned u1 = pack_bf16x2(v.z, v.w);
        *(uint2*)&os[bb * POUT + q * 4] = make_uint2(u0, u1);
    }
    {
        const float4* src = (const float4*)(Wout + (size_t)a * HDIM * ODIM);
        for (int idx = tid; idx < HDIM * ODIM / 4; idx += 256)
            ((float4*)wout_s)[idx] = src[idx];
    }
    __syncthreads();

    {
        const float* wA[3] = { Wo + n0, Wo + n0 + 16, Wo + n0 + 32 };
        f32x4 acc[4][3];
        #pragma unroll
        for (int i = 0; i < 4; i++)
            #pragma unroll
            for (int t = 0; t < 3; t++) acc[i][t] = (f32x4)0.f;
        gemm_bpass<4, ADIMM, 3, 4, HDIM, POUT>(acc, wA, os, lane);
        #pragma unroll
        for (int t = 0; t < 3; t++) {
            int col = n0 + 16 * t + r;
            float bb = bo[col];
            #pragma unroll
            for (int rg = 0; rg < 4; rg++)
                #pragma unroll
                for (int i = 0; i < 4; i++) {
                    int row = 16 * rg + 4 * g + i;
                    float v = h3v[t][rg][i] + acc[rg][t][i] + bb;
                    att[row * PA + col] = (__bf16)v;
                }
        }
    }
    __syncthreads();

    {
        float wb[48];
        #pragma unroll
        for (int c = 0; c < 6; c++)
            #pragma unroll
            for (int j = 0; j < 8; j++) {
                int k = c * 32 + g * 8 + j;
                wb[c * 8 + j] = (r < ODIM) ? wout_s[k * ODIM + r] : 0.f;
            }
        f32x4 oacc = (f32x4)0.f;
        #pragma unroll
        for (int c = 0; c < 6; c++) {
            bf16x8 bf;
            #pragma unroll
            for (int j = 0; j < 8; j++) bf[j] = (__bf16)wb[c * 8 + j];
            bf16x8 af = *(const bf16x8*)&att[(16 * wave + r) * PA + c * 32 + g * 8];
            oacc = __builtin_amdgcn_mfma_f32_16x16x32_bf16(af, bf, oacc, 0, 0, 0);
        }
        if (r < ODIM) {
            float bb = bout[a * ODIM + r];
            #pragma unroll
            for (int i = 0; i < 4; i++) {
                int row = 16 * wave + 4 * g + i;
                out[((size_t)a * BATCH + row) * ODIM + r] = oacc[i] + bb;
            }
        }
    }
}

// ---------------------------------------------------------------------------
extern "C" void kernel_launch(void* const* d_in, const int* in_sizes, int n_in,
                              void* d_out, int out_size, void* d_ws, size_t ws_size,
                              hipStream_t stream)
{
    const float* x       = (const float*)d_in[0];
    const float* ln_in_g = (const float*)d_in[1];
    const float* ln_in_b = (const float*)d_in[2];
    const float* W1      = (const float*)d_in[3];
    const float* b1      = (const float*)d_in[4];
    const float* Ws1     = (const float*)d_in[5];
    const float* bs1     = (const float*)d_in[6];
    const float* W2      = (const float*)d_in[7];
    const float* b2      = (const float*)d_in[8];
    const float* Ws2     = (const float*)d_in[9];
    const float* bs2     = (const float*)d_in[10];
    const float* W3      = (const float*)d_in[11];
    const float* b3      = (const float*)d_in[12];
    const float* ln_h_g  = (const float*)d_in[13];
    const float* ln_h_b  = (const float*)d_in[14];
    const float* Wout    = (const float*)d_in[15];
    const float* bout    = (const float*)d_in[16];
    const float* aln_g   = (const float*)d_in[17];
    const float* aln_b   = (const float*)d_in[18];
    const float* Wq      = (const float*)d_in[19];
    const float* bq      = (const float*)d_in[20];
    const float* Wk      = (const float*)d_in[21];
    const float* bk      = (const float*)d_in[22];
    const float* Wv      = (const float*)d_in[23];
    const float* bv      = (const float*)d_in[24];
    const float* Wo      = (const float*)d_in[25];
    const float* bo      = (const float*)d_in[26];
    float* out = (float*)d_out;

    float* ws = (float*)d_ws;
    const size_t H3_SZ = (size_t)AGENTS * BATCH * HDIM;
    const size_t QT_SZ = (size_t)BATCH * NHEADS * AGENTS * HEADD;
    float* h3 = ws;
    float* qT = h3 + H3_SZ;
    float* kT = qT + QT_SZ;
    float* vT = kT + QT_SZ;
    float* oT = vT + QT_SZ;

    mlp_kernel<<<AGENTS, 256, 0, stream>>>(x, ln_in_g, ln_in_b,
                                           W1, b1, Ws1, bs1, W2, b2, Ws2, bs2,
                                           W3, b3, ln_h_g, ln_h_b, h3);
    qkv_kernel<<<AGENTS, 256, 0, stream>>>(h3, aln_g, aln_b,
                                           Wq, bq, Wk, bk, Wv, bv, qT, kT, vT);
    attn_kernel<<<BATCH * NHEADS, 256, 0, stream>>>(qT, kT, vT, oT);
    out_kernel<<<AGENTS, 256, 0, stream>>>(h3, oT, Wo, bo, Wout, bout, out);
}